// Round 3
// baseline (1483.453 us; speedup 1.0000x reference)
//
#include <hip/hip_runtime.h>
#include <cfloat>
#include <cmath>

#define B_ 1024
#define D_ 256
#define H_ 512
#define N_ 100000
#define K_ 96
#define C_ 10
#define SAMP 4096      // sample columns for threshold estimation (fp32 sims
                       // overlay candV exactly: B*SAMP*4 == B*CAPC*4)
#define CAPC 4096      // per-row candidate capacity (expected ~2344 survivors)
#define RCAP 15        // legacy (gemm_nt MODE5, no longer instantiated)
#define NCT 1563       // ceil(N/64) B-chunks for sim_filter
#define NSTRIP 32      // N-strips for sim_filter (grid = 8 * 32 = 256)

typedef __attribute__((ext_vector_type(8))) short bf16x8;
typedef __attribute__((ext_vector_type(4))) float f32x4;

__device__ __forceinline__ float bf2f(ushort h) {
    union { unsigned u; float f; } v; v.u = ((unsigned)h) << 16; return v.f;
}
__device__ __forceinline__ ushort f2bf(float f) {
    union { float f; unsigned u; } v; v.f = f;
    unsigned u = v.u;
    unsigned r = (u + 0x7fffu + ((u >> 16) & 1u)) >> 16;
    return (ushort)r;
}
// monotone fp32 -> u32 (ascending)
__device__ __forceinline__ unsigned f2key(float f) {
    unsigned u = __float_as_uint(f);
    return (u & 0x80000000u) ? ~u : (u | 0x80000000u);
}
// d^2 from raw dot product -- single definition shared by thr_select and the
// fused filter so sample-column recompute is bitwise identical.
__device__ __forceinline__ float d2_of(float acc, float q2, float c2) {
    return fmaxf(fmaf(-2.f, acc, q2 + c2), 0.f);
}

#define GLDS(g, l)                                                            \
    __builtin_amdgcn_global_load_lds(                                         \
        (const __attribute__((address_space(1))) void*)(g),                   \
        (__attribute__((address_space(3))) void*)(l), 16, 0, 0)

#define FENCE() asm volatile("" ::: "memory")

// ---------------------------------------------------------------------------
// fp32 tiled GEMM (kept for tiny fp32 GEMMs: Wc, xe, xk)
// ---------------------------------------------------------------------------
template <int RELU>
__global__ __launch_bounds__(256) void gemm_nn(const float* __restrict__ A,
                                               const float* __restrict__ Bm,
                                               const float* __restrict__ bias,
                                               float* __restrict__ Cm,
                                               int M, int N, int Kd) {
    __shared__ float sA[16][68];
    __shared__ float sB[16][64];
    const int t  = threadIdx.x;
    const int tx = t & 15, ty = t >> 4;
    const int m0 = blockIdx.y * 64;
    const int n0 = blockIdx.x * 64;
    const int lr = t >> 2;
    const int lk = (t & 3) << 2;
    const int bk = t >> 4;
    const int bn = (t & 15) << 2;

    float acc[4][4] = {};
    for (int k0 = 0; k0 < Kd; k0 += 16) {
        float4 av = make_float4(0.f, 0.f, 0.f, 0.f);
        if (m0 + lr < M)
            av = *(const float4*)(A + (size_t)(m0 + lr) * Kd + k0 + lk);
        sA[lk + 0][lr] = av.x; sA[lk + 1][lr] = av.y;
        sA[lk + 2][lr] = av.z; sA[lk + 3][lr] = av.w;
        float4 bv = *(const float4*)(Bm + (size_t)(k0 + bk) * N + n0 + bn);
        *(float4*)&sB[bk][bn] = bv;
        __syncthreads();
#pragma unroll
        for (int kk = 0; kk < 16; ++kk) {
            float4 a4 = *(const float4*)&sA[kk][ty << 2];
            float4 b4 = *(const float4*)&sB[kk][tx << 2];
            float ar[4] = {a4.x, a4.y, a4.z, a4.w};
            float br[4] = {b4.x, b4.y, b4.z, b4.w};
#pragma unroll
            for (int i = 0; i < 4; ++i)
#pragma unroll
                for (int j = 0; j < 4; ++j)
                    acc[i][j] = fmaf(ar[i], br[j], acc[i][j]);
        }
        __syncthreads();
    }
#pragma unroll
    for (int i = 0; i < 4; ++i) {
        int row = m0 + (ty << 2) + i;
        if (row < M) {
            int col = n0 + (tx << 2);
            float b0 = 0.f, b1 = 0.f, b2 = 0.f, b3 = 0.f;
            if (bias) { b0 = bias[col]; b1 = bias[col + 1]; b2 = bias[col + 2]; b3 = bias[col + 3]; }
            float4 o;
            o.x = acc[i][0] + b0; o.y = acc[i][1] + b1;
            o.z = acc[i][2] + b2; o.w = acc[i][3] + b3;
            if (RELU) {
                o.x = fmaxf(o.x, 0.f); o.y = fmaxf(o.y, 0.f);
                o.z = fmaxf(o.z, 0.f); o.w = fmaxf(o.w, 0.f);
            }
            *(float4*)(Cm + (size_t)row * N + col) = o;
        }
    }
}

// ---------------------------------------------------------------------------
// bf16 MFMA NT GEMM: C = epilogue(A[M,K] @ B[N,K]^T)
// 128x128 tile, BK=32, 4 waves, each 4x4 tiles of 16x16x32 MFMA.
// SWZ=0: 2-D grid. SWZ=1: 1-D grid, 8 M-tiles sharing a B-tile on one XCD
// (needs M==1024). SWZ=2: 1-D grid, 4 N-tiles sharing an A-tile on one XCD
// (needs Nlim==512).
// MODE 0: out bf16     MODE 1: +bias, relu, out bf16
// MODE 2: raw dot product -> fp32 Cout
// MODE 3: +bias (no relu), out bf16
// ---------------------------------------------------------------------------
template <int MODE, int SWZ>
__global__ __launch_bounds__(256) void gemm_nt(const ushort* __restrict__ A,
                                               const ushort* __restrict__ Bv,
                                               const float* __restrict__ bias,
                                               void* __restrict__ Cout,
                                               int M, int Nlim, int K,
                                               int ldc, int nvalid, int per) {
    int m0, n0;
    if (SWZ == 0) {
        m0 = blockIdx.y * 128; n0 = blockIdx.x * 128;
    } else if (SWZ == 1) {
        int bid = blockIdx.x;
        int xcd = bid & 7, slot = bid >> 3;
        m0 = (slot & 7) * 128;
        n0 = (xcd * per + (slot >> 3)) * 128;
        if (n0 >= nvalid || m0 >= M) return;
    } else {
        int bid = blockIdx.x;
        int xcd = bid & 7, slot = bid >> 3;
        n0 = (slot & 3) * 128;
        m0 = (xcd * per + (slot >> 2)) * 128;
        if (m0 >= M) return;
    }

    __shared__ __align__(16) char smem[16896];
    ushort* sA = (ushort*)smem;            // 8192 B
    ushort* sB = (ushort*)(smem + 8192);   // 8192 B
    const int t = threadIdx.x;
    const int lane = t & 63, w = t >> 6;
    const int wm = w & 1, wn = w >> 1;

    f32x4 acc[4][4];
#pragma unroll
    for (int i = 0; i < 4; ++i)
#pragma unroll
        for (int j = 0; j < 4; ++j)
            acc[i][j] = (f32x4){0.f, 0.f, 0.f, 0.f};

    const int la = lane & 15, lk = lane >> 4;
    const int aoff = (wm * 64 + la) * 64 + lk * 16;
    const int boff = (wn * 64 + la) * 64 + lk * 16;
    const int r_ = t >> 2, cc_ = (t & 3);

    for (int k0 = 0; k0 < K; k0 += 32) {
#pragma unroll
        for (int q = 0; q < 2; ++q) {
            int r = r_ + q * 64;
            int ar = m0 + r; ar = (ar < M) ? ar : (M - 1);
            GLDS(A + (size_t)ar * K + k0 + cc_ * 8, (char*)sA + (q * 256 + t) * 16);
            int br = n0 + r; br = (br < Nlim) ? br : (Nlim - 1);
            GLDS(Bv + (size_t)br * K + k0 + cc_ * 8, (char*)sB + (q * 256 + t) * 16);
        }
        __syncthreads();
        bf16x8 af[4], bfr[4];
#pragma unroll
        for (int i = 0; i < 4; ++i)
            af[i] = *(const bf16x8*)((const char*)sA + aoff + i * 1024);
#pragma unroll
        for (int j = 0; j < 4; ++j)
            bfr[j] = *(const bf16x8*)((const char*)sB + boff + j * 1024);
#pragma unroll
        for (int i = 0; i < 4; ++i)
#pragma unroll
            for (int j = 0; j < 4; ++j)
                acc[i][j] = __builtin_amdgcn_mfma_f32_16x16x32_bf16(
                    af[i], bfr[j], acc[i][j], 0, 0, 0);
        __syncthreads();
    }

    const int rl = (lane >> 4) * 4, cl = lane & 15;

#pragma unroll
    for (int i = 0; i < 4; ++i) {
#pragma unroll
        for (int j = 0; j < 4; ++j) {
            int gc = n0 + wn * 64 + j * 16 + cl;
#pragma unroll
            for (int v = 0; v < 4; ++v) {
                int gr = m0 + wm * 64 + i * 16 + rl + v;
                if (gr < M && gc < nvalid) {
                    float val = acc[i][j][v];
                    if (MODE == 2) {
                        ((float*)Cout)[(size_t)gr * ldc + gc] = val;
                    } else {
                        if (MODE == 1 || MODE == 3) val += bias[gc];
                        if (MODE == 1) val = fmaxf(val, 0.f);
                        ((ushort*)Cout)[(size_t)gr * ldc + gc] = f2bf(val);
                    }
                }
            }
        }
    }
}

// ---------------------------------------------------------------------------
// NEW stage-3b kernel: persistent-A, streamed-B fused sim filter.
// A-tile (128 rows x 256 k, 64KB) loaded to LDS once; all A-fragments hoisted
// to registers once (aR[2][8], 64 VGPR/lane). B (cxb) streamed in 64-row
// full-K chunks through a 2x32KB double buffer: 8 GLDS/thread per chunk,
// counted vmcnt(8) (never 0 in steady state), 2 barriers per chunk
// (vs 2 per 32-k step in gemm_nt). T2 granule-XOR swizzle on both A and B
// (pre-swizzled GLDS *source*, linear LDS dest, swizzled ds_read) keeps
// ds_read_b128 at 2-way (free). Filter epilogue split into 8 pieces
// interleaved after each kf's 8-MFMA group, on a DOUBLE-BUFFERED accumulator
// so filter(chunk c-1) VALU hides under MFMA(chunk c).
// Accumulation = ascending 32-k MFMA chunks, bf16 inputs identical to
// gemm_nt's => dot products bitwise-identical to stage 3a (threshold exact).
// Grid: 256 blocks = 8 M-tiles x 32 N-strips; 1 block/CU (128KB LDS);
// strip-sharers (8 M-tiles of one strip group) co-located per XCD.
// ---------------------------------------------------------------------------
#define MFMA_(a, b, c) __builtin_amdgcn_mfma_f32_16x16x32_bf16(a, b, c, 0, 0, 0)

#define FILT_PIECE(ACCP, PN, KF)                                              \
    {                                                                         \
        int gc_ = (PN) + ((KF) & 3) * 16 + la;                                \
        float c2c_ = (gc_ < nvalid) ? c2v[gc_] : 3.0e38f;                     \
        _Pragma("unroll")                                                     \
        for (int v_ = 0; v_ < 4; ++v_) {                                      \
            float d2_ = d2_of(ACCP[(KF) >> 2][(KF) & 3][v_],                  \
                              q2r[((KF) >> 2) * 4 + v_], c2c_);               \
            if (d2_ <= thrr[((KF) >> 2) * 4 + v_]) {                          \
                int gm_ = gmr[((KF) >> 2) * 4 + v_];                          \
                int pp_ = atomicAdd(&cnt[gm_], 1);                            \
                if (pp_ < CAPC) {                                             \
                    candV[(size_t)gm_ * CAPC + pp_] = d2_;                    \
                    candI[(size_t)gm_ * CAPC + pp_] = gc_;                    \
                }                                                             \
            }                                                                 \
        }                                                                     \
        ACCP[(KF) >> 2][(KF) & 3] = (f32x4){0.f, 0.f, 0.f, 0.f};              \
    }

#define CHUNK_BODY(ACCC, ACCP, BUFOFF, PN, HASPREV)                           \
    do {                                                                      \
        const char* bp_ = sB + (BUFOFF) + la * 512;                           \
        _Pragma("unroll")                                                     \
        for (int kf = 0; kf < 8; ++kf) {                                      \
            int g_ = (((kf * 4 + lk) ^ sw) << 4);                             \
            bf16x8 b0_ = *(const bf16x8*)(bp_ + g_);                          \
            bf16x8 b1_ = *(const bf16x8*)(bp_ + 8192 + g_);                   \
            bf16x8 b2_ = *(const bf16x8*)(bp_ + 16384 + g_);                  \
            bf16x8 b3_ = *(const bf16x8*)(bp_ + 24576 + g_);                  \
            ACCC[0][0] = MFMA_(aR[0][kf], b0_, ACCC[0][0]);                   \
            ACCC[0][1] = MFMA_(aR[0][kf], b1_, ACCC[0][1]);                   \
            ACCC[0][2] = MFMA_(aR[0][kf], b2_, ACCC[0][2]);                   \
            ACCC[0][3] = MFMA_(aR[0][kf], b3_, ACCC[0][3]);                   \
            ACCC[1][0] = MFMA_(aR[1][kf], b0_, ACCC[1][0]);                   \
            ACCC[1][1] = MFMA_(aR[1][kf], b1_, ACCC[1][1]);                   \
            ACCC[1][2] = MFMA_(aR[1][kf], b2_, ACCC[1][2]);                   \
            ACCC[1][3] = MFMA_(aR[1][kf], b3_, ACCC[1][3]);                   \
            if (HASPREV) FILT_PIECE(ACCP, PN, kf)                             \
        }                                                                     \
    } while (0)

#define POST_STAGE(CC)                                                        \
    do {                                                                      \
        FENCE(); __builtin_amdgcn_s_barrier();                                \
        int cs_ = (CC) + 2;                                                   \
        if (cs_ < c1) {                                                       \
            stage_b(cs_, (((CC)-c0) & 1) * 32768);                            \
            asm volatile("s_waitcnt vmcnt(8)" ::: "memory");                  \
        } else {                                                              \
            asm volatile("s_waitcnt vmcnt(0)" ::: "memory");                  \
        }                                                                     \
        __builtin_amdgcn_s_barrier(); FENCE();                                \
    } while (0)

__global__ __launch_bounds__(256, 1) void sim_filter(
    const ushort* __restrict__ A, const ushort* __restrict__ Bv,
    const float* __restrict__ q2v, const float* __restrict__ c2v,
    const float* __restrict__ thrv, float* __restrict__ candV,
    int* __restrict__ candI, int* __restrict__ cnt, int nvalid) {
    __shared__ __align__(16) char smem[131072];
    char* sA = smem;             // [128 rows][32 granules of 16B], swizzled
    char* sB = smem + 65536;     // 2 bufs x [64 rows][32 granules]

    const int t = threadIdx.x;
    const int lane = t & 63, w = t >> 6;
    const int la = lane & 15, lk = lane >> 4, sw = la & 7;

    const int bid = blockIdx.x;
    const int mt = bid >> 5;                               // 0..7
    const int strip = ((bid & 7) << 2) | ((bid >> 3) & 3); // 0..31, XCD-local
    const int m0 = mt << 7;
    const int c0 = strip * NCT / NSTRIP;
    const int c1 = (strip + 1) * NCT / NSTRIP;

    // staging geometry: LDS granule gidx = i*256+t (linear dest);
    // row = i*8 + (t>>5), src granule = (t&31) ^ ((t>>5)&7)  (involution)
    const int trow = t >> 5;
    const int sw8 = ((t & 31) ^ (trow & 7)) << 3;   // src elem offset

    auto stage_b = [&](int ck, int bufoff) {
        char* d = sB + bufoff + t * 16;
        size_t nb = (size_t)ck << 6;
#pragma unroll
        for (int i = 0; i < 8; ++i) {
            long rg = (long)nb + i * 8 + trow;
            if (rg >= nvalid) rg = nvalid - 1;
            GLDS(Bv + (size_t)rg * 256 + sw8, d + i * 4096);
        }
    };

    // ---- prologue: A-tile + first two B chunks ----
    {
        char* dA = sA + t * 16;
#pragma unroll
        for (int i = 0; i < 16; ++i) {
            int row = m0 + i * 8 + trow;
            GLDS(A + (size_t)row * 256 + sw8, dA + i * 4096);
        }
    }
    stage_b(c0, 0);
    int cpre = (c0 + 1 < c1) ? c0 + 1 : c0;
    stage_b(cpre, 32768);
    asm volatile("s_waitcnt vmcnt(8)" ::: "memory");
    __builtin_amdgcn_s_barrier(); FENCE();

    // ---- hoist A fragments to registers (once per block) ----
    bf16x8 aR[2][8];
    {
        const char* ap = sA + (w * 32 + la) * 512;
#pragma unroll
        for (int mf = 0; mf < 2; ++mf)
#pragma unroll
            for (int ks = 0; ks < 8; ++ks)
                aR[mf][ks] = *(const bf16x8*)(ap + mf * 8192 +
                                              (((ks * 4 + lk) ^ sw) << 4));
    }

    // ---- per-block row constants (q2, thr, global row ids) ----
    int gmr[8]; float q2r[8], thrr[8];
#pragma unroll
    for (int mf = 0; mf < 2; ++mf)
#pragma unroll
        for (int v = 0; v < 4; ++v) {
            int gm = m0 + w * 32 + mf * 16 + lk * 4 + v;
            gmr[mf * 4 + v] = gm;
            q2r[mf * 4 + v] = q2v[gm];
            thrr[mf * 4 + v] = thrv[gm];
        }

    f32x4 acc0[2][4], acc1[2][4];
#pragma unroll
    for (int i = 0; i < 2; ++i)
#pragma unroll
        for (int j = 0; j < 4; ++j) {
            acc0[i][j] = (f32x4){0.f, 0.f, 0.f, 0.f};
            acc1[i][j] = (f32x4){0.f, 0.f, 0.f, 0.f};
        }

    // ---- chunk loop: compute acc for chunk c, filter chunk c-1 ----
    CHUNK_BODY(acc0, acc1, 0, 0, false);
    POST_STAGE(c0);
    int pn = c0 * 64;
    int c = c0 + 1;
    for (; c + 1 < c1; c += 2) {
        CHUNK_BODY(acc1, acc0, 32768, pn, true);
        POST_STAGE(c);
        pn = c * 64;
        CHUNK_BODY(acc0, acc1, 0, pn, true);
        POST_STAGE(c + 1);
        pn = (c + 1) * 64;
    }
    if (c < c1) {
        CHUNK_BODY(acc1, acc0, 32768, pn, true);
        POST_STAGE(c);
        pn = c * 64;
#pragma unroll
        for (int p8 = 0; p8 < 8; ++p8) FILT_PIECE(acc1, pn, p8);
    } else {
#pragma unroll
        for (int p8 = 0; p8 < 8; ++p8) FILT_PIECE(acc0, pn, p8);
    }
}

// ---------------------------------------------------------------------------
// per-row radix-select of the 96th-SMALLEST d^2 over the first SAMP columns.
// ---------------------------------------------------------------------------
__global__ __launch_bounds__(256) void thr_select(const float* __restrict__ S,
                                                  int ld,
                                                  const float* __restrict__ q2v,
                                                  const float* __restrict__ c2v,
                                                  float* __restrict__ thrArr) {
    __shared__ unsigned keys[SAMP];
    __shared__ int hist[256];
    __shared__ int sel[2];
    const int b = blockIdx.x, t = threadIdx.x;
    const float q2b = q2v[b];
    for (int i = t; i < SAMP; i += 256)
        keys[i] = ~f2key(d2_of(S[(size_t)b * ld + i], q2b, c2v[i]));
    __syncthreads();
    unsigned prefix = 0, mask = 0;
    int rank = K_;
    for (int shift = 24; shift >= 0; shift -= 8) {
        hist[t & 255] = 0;
        __syncthreads();
        for (int i = t; i < SAMP; i += 256) {
            unsigned k = keys[i];
            if ((k & mask) == prefix) atomicAdd(&hist[(k >> shift) & 255], 1);
        }
        __syncthreads();
        if (t == 0) {
            int r = rank, d = 255;
            for (; d > 0; --d) { int c = hist[d]; if (r - c <= 0) break; r -= c; }
            sel[0] = d; sel[1] = (r < 1) ? 1 : r;
        }
        __syncthreads();
        prefix |= ((unsigned)sel[0]) << shift;
        rank = sel[1];
        mask |= (0xFFu << shift);
        __syncthreads();
    }
    if (t == 0) {
        unsigned key = ~prefix;
        thrArr[b] = __uint_as_float(key & 0x7FFFFFFFu);
    }
}

// ---------------------------------------------------------------------------
// per-row exact 96-smallest-d2 from candidate buffer via radix select
// (inverted keys) + compaction. topV receives d2.
// ---------------------------------------------------------------------------
__global__ __launch_bounds__(256) void final_select(const float* __restrict__ candV,
                                                    const int* __restrict__ candI,
                                                    const int* __restrict__ cnt,
                                                    float* __restrict__ topV,
                                                    int* __restrict__ topI) {
    __shared__ unsigned keys[CAPC];
    __shared__ int hist[256];
    __shared__ int sel[2];
    __shared__ int poscnt, eqcnt;
    const int b = blockIdx.x, t = threadIdx.x;
    int n = cnt[b]; if (n > CAPC) n = CAPC;
    for (int i = t; i < n; i += 256)
        keys[i] = ~f2key(candV[(size_t)b * CAPC + i]);
    __syncthreads();
    unsigned prefix = 0, mask = 0;
    int rank = K_;
    for (int shift = 24; shift >= 0; shift -= 8) {
        hist[t & 255] = 0;
        __syncthreads();
        for (int i = t; i < n; i += 256) {
            unsigned k = keys[i];
            if ((k & mask) == prefix) atomicAdd(&hist[(k >> shift) & 255], 1);
        }
        __syncthreads();
        if (t == 0) {
            int r = rank, d = 255;
            for (; d > 0; --d) { int c = hist[d]; if (r - c <= 0) break; r -= c; }
            sel[0] = d; sel[1] = (r < 1) ? 1 : r;
        }
        __syncthreads();
        prefix |= ((unsigned)sel[0]) << shift;
        rank = sel[1];
        mask |= (0xFFu << shift);
        __syncthreads();
    }
    unsigned kth = prefix;
    if (t == 0) { poscnt = 0; eqcnt = 0; }
    __syncthreads();
    for (int i = t; i < n; i += 256) {
        if (keys[i] > kth) {
            int p = atomicAdd(&poscnt, 1);
            topV[b * K_ + p] = candV[(size_t)b * CAPC + i];
            topI[b * K_ + p] = candI[(size_t)b * CAPC + i];
        }
    }
    __syncthreads();
    int base = poscnt;
    for (int i = t; i < n; i += 256) {
        if (keys[i] == kth) {
            int p = atomicAdd(&eqcnt, 1);
            if (base + p < K_) {
                topV[b * K_ + base + p] = candV[(size_t)b * CAPC + i];
                topI[b * K_ + base + p] = candI[(size_t)b * CAPC + i];
            }
        }
    }
}

__global__ void init_cnt(int* cnt) {
    int i = blockIdx.x * 256 + threadIdx.x;
    if (i < B_) cnt[i] = 0;
}

// ---------------------------------------------------------------------------
__global__ void conv_f2b(const float* __restrict__ in, ushort* __restrict__ out, int n) {
    int i = (blockIdx.x * 256 + threadIdx.x) * 4;
    int stride = gridDim.x * 256 * 4;
    for (; i < n; i += stride) {
        float4 v = *(const float4*)(in + i);
        ushort4 o;
        o.x = f2bf(v.x); o.y = f2bf(v.y); o.z = f2bf(v.z); o.w = f2bf(v.w);
        *(ushort4*)(out + i) = o;
    }
}

__global__ __launch_bounds__(256) void transpose_f2b(const float* __restrict__ in,
                                                     ushort* __restrict__ out,
                                                     int R, int Cn) {
    __shared__ float tile[32][33];
    int bx = blockIdx.x * 32, by = blockIdx.y * 32;
    int tx = threadIdx.x & 31, ty = threadIdx.x >> 5;
    int x = bx + tx;
#pragma unroll
    for (int dy = 0; dy < 32; dy += 8) {
        int y = by + ty + dy;
        if (x < Cn && y < R) tile[ty + dy][tx] = in[(size_t)y * Cn + x];
    }
    __syncthreads();
    int ox = by + tx;
#pragma unroll
    for (int dy = 0; dy < 32; dy += 8) {
        int oy = bx + ty + dy;
        if (ox < R && oy < Cn) out[(size_t)oy * R + ox] = f2bf(tile[tx][ty + dy]);
    }
}

__global__ __launch_bounds__(64) void rowsq_b(const ushort* __restrict__ X,
                                              float* __restrict__ outv) {
    const int r = blockIdx.x, t = threadIdx.x;
    const ushort* p = X + (size_t)r * H_;
    ushort4 a = *(const ushort4*)(p + t * 4);
    ushort4 b = *(const ushort4*)(p + 256 + t * 4);
    float ax = bf2f(a.x), ay = bf2f(a.y), az = bf2f(a.z), aw = bf2f(a.w);
    float bx = bf2f(b.x), by = bf2f(b.y), bz = bf2f(b.z), bw = bf2f(b.w);
    float v = ax * ax + ay * ay + az * az + aw * aw +
              bx * bx + by * by + bz * bz + bw * bw;
    for (int off = 32; off > 0; off >>= 1) v += __shfl_down(v, off);
    if (t == 0) outv[r] = v;
}

// q2x[b] = ||xkb[b,:]||^2 - 2 * dot(xk[b,:], bc)   (folds the bias term of
// sim = xproj.cx + xk.bc into the per-row q2 constant)
__global__ __launch_bounds__(64) void q2x_k(const ushort* __restrict__ Xb,
                                            const float* __restrict__ Xf,
                                            const float* __restrict__ bc,
                                            float* __restrict__ outv) {
    const int r = blockIdx.x, t = threadIdx.x;
    const ushort* p  = Xb + (size_t)r * H_ + t * 8;
    const float*  xf = Xf + (size_t)r * H_ + t * 8;
    float nrm = 0.f, dot = 0.f;
#pragma unroll
    for (int j = 0; j < 8; ++j) {
        float v = bf2f(p[j]);
        nrm = fmaf(v, v, nrm);
        dot = fmaf(xf[j], bc[t * 8 + j], dot);
    }
    for (int off = 32; off > 0; off >>= 1) {
        nrm += __shfl_down(nrm, off);
        dot += __shfl_down(dot, off);
    }
    if (t == 0) outv[r] = nrm - 2.f * dot;
}

__global__ void bcomb_k(const float* __restrict__ b_enc,
                        const float* __restrict__ W_key,
                        const float* __restrict__ b_key,
                        float* __restrict__ b_comb) {
    int h = blockIdx.x * 256 + threadIdx.x;
    if (h >= H_) return;
    float acc = b_key[h];
    for (int m = 0; m < H_; ++m)
        acc = fmaf(b_enc[m], W_key[(size_t)m * H_ + h], acc);
    b_comb[h] = acc;
}

__global__ __launch_bounds__(128) void softmax_k(const float* __restrict__ topVal,
                                                 float* __restrict__ attn) {
    __shared__ float red[128];
    const int b = blockIdx.x, t = threadIdx.x;
    float v = (t < K_) ? -sqrtf(topVal[b * K_ + t]) : -FLT_MAX;
    red[t] = v; __syncthreads();
    for (int s = 64; s > 0; s >>= 1) {
        if (t < s) red[t] = fmaxf(red[t], red[t + s]);
        __syncthreads();
    }
    float m = red[0]; __syncthreads();
    float e = (t < K_) ? expf(v - m) : 0.f;
    red[t] = e; __syncthreads();
    for (int s = 64; s > 0; s >>= 1) {
        if (t < s) red[t] += red[t + s];
        __syncthreads();
    }
    float ssum = red[0];
    if (t < K_) attn[b * K_ + t] = e / ssum;
}

__global__ __launch_bounds__(128) void gather_diff_b(const float* __restrict__ XK,
                                                     const ushort* __restrict__ CK,
                                                     const int* __restrict__ topI,
                                                     ushort* __restrict__ diff,
                                                     int b0) {
    const int r = blockIdx.x;
    const int b = b0 + r / K_;
    const int idx = topI[b * K_ + (r % K_)];
    const int t = threadIdx.x;
    float4 xv = *(const float4*)(XK + (size_t)b * H_ + t * 4);
    ushort4 cv = *(const ushort4*)(CK + (size_t)idx * H_ + t * 4);
    ushort4 o;
    o.x = f2bf(xv.x - bf2f(cv.x));
    o.y = f2bf(xv.y - bf2f(cv.y));
    o.z = f2bf(xv.z - bf2f(cv.z));
    o.w = f2bf(xv.w - bf2f(cv.w));
    *(ushort4*)(diff + (size_t)r * H_ + t * 4) = o;
}

// attn-weighted reduction of h over k (BEFORE the W_t2 GEMM):
// hw[b,:] = sum_k attn[b,k] * h[(b-b0)*K+k, :]   (fp32 accum -> bf16)
__global__ __launch_bounds__(256) void wsum_h(const float* __restrict__ attn,
                                              const ushort* __restrict__ h,
                                              ushort* __restrict__ hw, int b0) {
    const int bl = blockIdx.x;
    const int b = b0 + bl;
    const int t = threadIdx.x;
    float a0 = 0.f, a1 = 0.f;
    const float* ap = attn + b * K_;
    for (int k = 0; k < K_; ++k) {
        float w = ap[k];
        const ushort* hr = h + (size_t)(bl * K_ + k) * H_;
        a0 = fmaf(w, bf2f(hr[t]), a0);
        a1 = fmaf(w, bf2f(hr[t + 256]), a1);
    }
    hw[(size_t)b * H_ + t]       = f2bf(a0);
    hw[(size_t)b * H_ + t + 256] = f2bf(a1);
}

// out = xe + sum_k attn*E[label[topI]] + tsum
__global__ __launch_bounds__(256) void final_out(const float* __restrict__ attn,
                                                 const int* __restrict__ topI,
                                                 const int* __restrict__ labels,
                                                 const float* __restrict__ E,
                                                 const float* __restrict__ tsum,
                                                 const float* __restrict__ xe,
                                                 float* __restrict__ out) {
    const int b = blockIdx.x, t = threadIdx.x;
    float a0 = 0.f, a1 = 0.f;
    for (int k = 0; k < K_; ++k) {
        float w = attn[b * K_ + k];
        int idx = topI[b * K_ + k];
        int lab = labels[idx];
        const float* el = E + (size_t)lab * H_;
        a0 = fmaf(w, el[t], a0);
        a1 = fmaf(w, el[t + 256], a1);
    }
    out[(size_t)b * H_ + t] =
        xe[(size_t)b * H_ + t] + a0 + tsum[(size_t)b * H_ + t];
    out[(size_t)b * H_ + t + 256] =
        xe[(size_t)b * H_ + t + 256] + a1 + tsum[(size_t)b * H_ + t + 256];
}

// ---------------------------------------------------------------------------
extern "C" void kernel_launch(void* const* d_in, const int* in_sizes, int n_in,
                              void* d_out, int out_size, void* d_ws, size_t ws_size,
                              hipStream_t stream) {
    const float* x      = (const float*)d_in[0];
    const float* cx     = (const float*)d_in[1];
    const int*   labels = (const int*)d_in[2];
    const float* W_enc  = (const float*)d_in[3];
    const float* b_enc  = (const float*)d_in[4];
    const float* W_key  = (const float*)d_in[5];
    const float* b_key  = (const float*)d_in[6];
    // d_in[7]=W_val, d_in[8]=b_val dead (gather unused in reference)
    const float* E_label = (const float*)d_in[9];
    const float* W_t1   = (const float*)d_in[10];
    const float* b_t1   = (const float*)d_in[11];
    const float* W_t2   = (const float*)d_in[12];
    float* out = (float*)d_out;

    char* base = (char*)d_ws;
    size_t off = 0;
    auto take = [&](size_t n) -> char* {
        char* p = base + off;
        off = (off + n + 255) & ~(size_t)255;
        return p;
    };
    float*  Wc    = (float*)take((size_t)D_ * H_ * 4);
    float*  bc    = (float*)take((size_t)H_ * 4);
    ushort* WcT   = (ushort*)take((size_t)H_ * D_ * 2);
    ushort* Wcb   = (ushort*)take((size_t)D_ * H_ * 2);   // Wc bf16 [D,H] rows=d
    ushort* Wt1T  = (ushort*)take((size_t)H_ * H_ * 2);
    ushort* Wt2T  = (ushort*)take((size_t)H_ * H_ * 2);
    float*  xe    = (float*)take((size_t)B_ * H_ * 4);
    float*  xk    = (float*)take((size_t)B_ * H_ * 4);
    ushort* xkb   = (ushort*)take((size_t)B_ * H_ * 2);
    ushort* xprojb= (ushort*)take((size_t)B_ * D_ * 2);   // xk @ Wc^T, bf16
    float*  q2x   = (float*)take((size_t)B_ * 4);
    ushort* ckb   = (ushort*)take((size_t)N_ * H_ * 2);
    float*  c2    = (float*)take((size_t)N_ * 4);
    float*  topV  = (float*)take((size_t)B_ * K_ * 4);
    int*    topI  = (int*)take((size_t)B_ * K_ * 4);
    float*  thr   = (float*)take((size_t)B_ * 4);
    float*  attn  = (float*)take((size_t)B_ * K_ * 4);
    int*    cnt   = (int*)take((size_t)B_ * 4);
    float*  candV = (float*)take((size_t)B_ * CAPC * 4);
    int*    candI = (int*)take((size_t)B_ * CAPC * 4);
    ushort* hwAll = (ushort*)take((size_t)B_ * H_ * 2);
    float*  tsum  = (float*)take((size_t)B_ * H_ * 4);
    char*   big   = base + off;      // shared: cxb (alive thru 3b) -> stage4 bufs
    size_t rem = (ws_size > off) ? (ws_size - off) : 0;

    ushort* cxb = (ushort*)big;       // N*D*2 = 51.2 MB (dead after stage 3b)
    // simSmall (B*SAMP*4 = 16.8 MB) overlays candV exactly (dead before 3b).
    float* simSmall = (float*)candV;

    long long bcq = (long long)(rem / ((size_t)K_ * H_ * 2 * 2));
    if (bcq > B_) bcq = B_;
    if (bcq < 1) bcq = 1;
    int Bc = (int)bcq;

    // stage 0: combined candidate weights + transposed bf16 weights
    {
        dim3 g(H_ / 64, D_ / 64);
        gemm_nn<0><<<g, 256, 0, stream>>>(W_enc, W_key, nullptr, Wc, D_, H_, H_);
        bcomb_k<<<(H_ + 255) / 256, 256, 0, stream>>>(b_enc, W_key, b_key, bc);
        dim3 gt1((H_ + 31) / 32, (D_ + 31) / 32);
        transpose_f2b<<<gt1, 256, 0, stream>>>(Wc, WcT, D_, H_);
        conv_f2b<<<128, 256, 0, stream>>>(Wc, Wcb, D_ * H_);
        dim3 gt2((H_ + 31) / 32, (H_ + 31) / 32);
        transpose_f2b<<<gt2, 256, 0, stream>>>(W_t1, Wt1T, H_, H_);
        transpose_f2b<<<gt2, 256, 0, stream>>>(W_t2, Wt2T, H_, H_);
    }
    // stage 1: query encodes (fp32, tiny) + bf16 conversions + xproj
    {
        dim3 gx(H_ / 64, B_ / 64);
        gemm_nn<0><<<gx, 256, 0, stream>>>(x, W_enc, b_enc, xe, B_, H_, D_);
        gemm_nn<0><<<gx, 256, 0, stream>>>(x, Wc, bc, xk, B_, H_, D_);
        conv_f2b<<<1024, 256, 0, stream>>>(xk, xkb, B_ * H_);
        conv_f2b<<<2048, 256, 0, stream>>>(cx, cxb, N_ * D_);
        // xproj[B,D] = xk @ Wc^T  (contract over H), bf16 out
        dim3 gp(D_ / 128, B_ / 128);         // (2, 8)
        gemm_nt<0, 0><<<gp, 256, 0, stream>>>(
            xkb, Wcb, nullptr, xprojb, B_, D_, H_, D_, D_, 0);
        q2x_k<<<B_, 64, 0, stream>>>(xkb, xk, bc, q2x);
    }
    // stage 2: candidate keys via bf16 MFMA (bias, no relu), SWZ=2
    {
        int mt = (N_ + 127) / 128;           // 782
        int mper = (mt + 7) / 8;             // 98
        gemm_nt<3, 2><<<8 * mper * 4, 256, 0, stream>>>(
            cxb, WcT, bc, ckb, N_, H_, D_, H_, H_, mper);
    }
    rowsq_b<<<N_, 64, 0, stream>>>(ckb, c2);

    // stage 3a: sample sim GEMM over D-contraction (first SAMP cols, raw dot)
    // sim = xproj . cx  (+ per-row constant folded into q2x)
    {
        int nper = (SAMP / 128 + 7) / 8;     // 4
        gemm_nt<2, 1><<<64 * nper, 256, 0, stream>>>(
            xprojb, cxb, nullptr, simSmall, B_, N_, D_, SAMP, SAMP, nper);
        thr_select<<<B_, 256, 0, stream>>>(simSmall, SAMP, q2x, c2, thr);
    }
    // stage 3b: persistent-A streamed-B fused sim filter (K=256)
    init_cnt<<<(B_ + 255) / 256, 256, 0, stream>>>(cnt);
    sim_filter<<<8 * NSTRIP, 256, 0, stream>>>(
        xprojb, cxb, q2x, c2, thr, candV, candI, cnt, N_);
    final_select<<<B_, 256, 0, stream>>>(candV, candI, cnt, topV, topI);
    softmax_k<<<B_, 128, 0, stream>>>(topV, attn);

    // stage 4: h = relu(diff@W1+b1); hw = sum_k attn*h (BEFORE W2);
    //          tsum = hw @ W2; out = xe + sum_k attn*E[label] + tsum
    ushort* diffB = (ushort*)big;
    ushort* hB = (ushort*)(big + (size_t)Bc * K_ * H_ * 2);
    for (int b0 = 0; b0 < B_; b0 += Bc) {
        int bcn = min(Bc, B_ - b0);
        int Mrows = bcn * K_;
        gather_diff_b<<<Mrows, 128, 0, stream>>>(xk, ckb, topI, diffB, b0);
        int mt4 = (Mrows + 127) / 128;
        int mper4 = (mt4 + 7) / 8;
        gemm_nt<1, 2><<<8 * mper4 * 4, 256, 0, stream>>>(
            diffB, Wt1T, b_t1, hB, Mrows, H_, H_, H_, H_, mper4);
        wsum_h<<<bcn, 256, 0, stream>>>(attn, hB, hwAll, b0);
    }
    {   // tiny GEMM: tsum[1024,512] = hwAll @ Wt2T^T (fp32 out via MODE 2)
        dim3 g(H_ / 128, B_ / 128);          // (4, 8)
        gemm_nt<2, 0><<<g, 256, 0, stream>>>(
            hwAll, Wt2T, nullptr, tsum, B_, H_, H_, H_, H_, 0);
    }
    final_out<<<B_, 256, 0, stream>>>(attn, topI, labels, E_label, tsum, xe, out);
}

// Round 4
// 994.233 us; speedup vs baseline: 1.4921x; 1.4921x over previous
//
#include <hip/hip_runtime.h>
#include <cfloat>
#include <cmath>

#define B_ 1024
#define D_ 256
#define H_ 512
#define N_ 100000
#define K_ 96
#define C_ 10
#define SAMP 4096      // sample columns for threshold estimation (fp32 sims
                       // overlay candV exactly: B*SAMP*4 == B*CAPC*4)
#define CAPC 4096      // per-row candidate capacity (expected ~2344 survivors)
#define NT3 782        // ceil(N/128) N-tiles for filt128
#define NSUB 4         // N-tiles per filt128 block (epilogue amortization)
#define NGRP ((NT3 + NSUB - 1) / NSUB)   // 196 groups
#define RCAP3 32       // per-row staging slots across NSUB tiles (mean ~12,
                       // P(Poisson(12)>32) ~ 1e-7; global fallback stays exact)

typedef __attribute__((ext_vector_type(8))) short bf16x8;
typedef __attribute__((ext_vector_type(4))) float f32x4;

__device__ __forceinline__ float bf2f(ushort h) {
    union { unsigned u; float f; } v; v.u = ((unsigned)h) << 16; return v.f;
}
__device__ __forceinline__ ushort f2bf(float f) {
    union { float f; unsigned u; } v; v.f = f;
    unsigned u = v.u;
    unsigned r = (u + 0x7fffu + ((u >> 16) & 1u)) >> 16;
    return (ushort)r;
}
// monotone fp32 -> u32 (ascending)
__device__ __forceinline__ unsigned f2key(float f) {
    unsigned u = __float_as_uint(f);
    return (u & 0x80000000u) ? ~u : (u | 0x80000000u);
}
// d^2 from raw dot product -- single definition shared by thr_select and the
// fused filter so sample-column recompute is bitwise identical.
__device__ __forceinline__ float d2_of(float acc, float q2, float c2) {
    return fmaxf(fmaf(-2.f, acc, q2 + c2), 0.f);
}

#define GLDS(g, l)                                                            \
    __builtin_amdgcn_global_load_lds(                                         \
        (const __attribute__((address_space(1))) void*)(g),                   \
        (__attribute__((address_space(3))) void*)(l), 16, 0, 0)

// ---------------------------------------------------------------------------
// fp32 tiled GEMM (kept for tiny fp32 GEMMs: Wc, xe, xk)
// ---------------------------------------------------------------------------
template <int RELU>
__global__ __launch_bounds__(256) void gemm_nn(const float* __restrict__ A,
                                               const float* __restrict__ Bm,
                                               const float* __restrict__ bias,
                                               float* __restrict__ Cm,
                                               int M, int N, int Kd) {
    __shared__ float sA[16][68];
    __shared__ float sB[16][64];
    const int t  = threadIdx.x;
    const int tx = t & 15, ty = t >> 4;
    const int m0 = blockIdx.y * 64;
    const int n0 = blockIdx.x * 64;
    const int lr = t >> 2;
    const int lk = (t & 3) << 2;
    const int bk = t >> 4;
    const int bn = (t & 15) << 2;

    float acc[4][4] = {};
    for (int k0 = 0; k0 < Kd; k0 += 16) {
        float4 av = make_float4(0.f, 0.f, 0.f, 0.f);
        if (m0 + lr < M)
            av = *(const float4*)(A + (size_t)(m0 + lr) * Kd + k0 + lk);
        sA[lk + 0][lr] = av.x; sA[lk + 1][lr] = av.y;
        sA[lk + 2][lr] = av.z; sA[lk + 3][lr] = av.w;
        float4 bv = *(const float4*)(Bm + (size_t)(k0 + bk) * N + n0 + bn);
        *(float4*)&sB[bk][bn] = bv;
        __syncthreads();
#pragma unroll
        for (int kk = 0; kk < 16; ++kk) {
            float4 a4 = *(const float4*)&sA[kk][ty << 2];
            float4 b4 = *(const float4*)&sB[kk][tx << 2];
            float ar[4] = {a4.x, a4.y, a4.z, a4.w};
            float br[4] = {b4.x, b4.y, b4.z, b4.w};
#pragma unroll
            for (int i = 0; i < 4; ++i)
#pragma unroll
                for (int j = 0; j < 4; ++j)
                    acc[i][j] = fmaf(ar[i], br[j], acc[i][j]);
        }
        __syncthreads();
    }
#pragma unroll
    for (int i = 0; i < 4; ++i) {
        int row = m0 + (ty << 2) + i;
        if (row < M) {
            int col = n0 + (tx << 2);
            float b0 = 0.f, b1 = 0.f, b2 = 0.f, b3 = 0.f;
            if (bias) { b0 = bias[col]; b1 = bias[col + 1]; b2 = bias[col + 2]; b3 = bias[col + 3]; }
            float4 o;
            o.x = acc[i][0] + b0; o.y = acc[i][1] + b1;
            o.z = acc[i][2] + b2; o.w = acc[i][3] + b3;
            if (RELU) {
                o.x = fmaxf(o.x, 0.f); o.y = fmaxf(o.y, 0.f);
                o.z = fmaxf(o.z, 0.f); o.w = fmaxf(o.w, 0.f);
            }
            *(float4*)(Cm + (size_t)row * N + col) = o;
        }
    }
}

// ---------------------------------------------------------------------------
// bf16 MFMA NT GEMM: C = epilogue(A[M,K] @ B[N,K]^T)
// 128x128 tile, BK=32, 4 waves, each 4x4 tiles of 16x16x32 MFMA.
// SWZ=0: 2-D grid. SWZ=1: 1-D grid, 8 M-tiles sharing a B-tile on one XCD
// (needs M==1024). SWZ=2: 1-D grid, 4 N-tiles sharing an A-tile on one XCD
// (needs Nlim==512).
// MODE 0: out bf16     MODE 1: +bias, relu, out bf16
// MODE 2: raw dot product -> fp32 Cout
// MODE 3: +bias (no relu), out bf16
// ---------------------------------------------------------------------------
template <int MODE, int SWZ>
__global__ __launch_bounds__(256) void gemm_nt(const ushort* __restrict__ A,
                                               const ushort* __restrict__ Bv,
                                               const float* __restrict__ bias,
                                               void* __restrict__ Cout,
                                               int M, int Nlim, int K,
                                               int ldc, int nvalid, int per) {
    int m0, n0;
    if (SWZ == 0) {
        m0 = blockIdx.y * 128; n0 = blockIdx.x * 128;
    } else if (SWZ == 1) {
        int bid = blockIdx.x;
        int xcd = bid & 7, slot = bid >> 3;
        m0 = (slot & 7) * 128;
        n0 = (xcd * per + (slot >> 3)) * 128;
        if (n0 >= nvalid || m0 >= M) return;
    } else {
        int bid = blockIdx.x;
        int xcd = bid & 7, slot = bid >> 3;
        n0 = (slot & 3) * 128;
        m0 = (xcd * per + (slot >> 2)) * 128;
        if (m0 >= M) return;
    }

    __shared__ __align__(16) char smem[16896];
    ushort* sA = (ushort*)smem;            // 8192 B
    ushort* sB = (ushort*)(smem + 8192);   // 8192 B
    const int t = threadIdx.x;
    const int lane = t & 63, w = t >> 6;
    const int wm = w & 1, wn = w >> 1;

    f32x4 acc[4][4];
#pragma unroll
    for (int i = 0; i < 4; ++i)
#pragma unroll
        for (int j = 0; j < 4; ++j)
            acc[i][j] = (f32x4){0.f, 0.f, 0.f, 0.f};

    const int la = lane & 15, lk = lane >> 4;
    const int aoff = (wm * 64 + la) * 64 + lk * 16;
    const int boff = (wn * 64 + la) * 64 + lk * 16;
    const int r_ = t >> 2, cc_ = (t & 3);

    for (int k0 = 0; k0 < K; k0 += 32) {
#pragma unroll
        for (int q = 0; q < 2; ++q) {
            int r = r_ + q * 64;
            int ar = m0 + r; ar = (ar < M) ? ar : (M - 1);
            GLDS(A + (size_t)ar * K + k0 + cc_ * 8, (char*)sA + (q * 256 + t) * 16);
            int br = n0 + r; br = (br < Nlim) ? br : (Nlim - 1);
            GLDS(Bv + (size_t)br * K + k0 + cc_ * 8, (char*)sB + (q * 256 + t) * 16);
        }
        __syncthreads();
        bf16x8 af[4], bfr[4];
#pragma unroll
        for (int i = 0; i < 4; ++i)
            af[i] = *(const bf16x8*)((const char*)sA + aoff + i * 1024);
#pragma unroll
        for (int j = 0; j < 4; ++j)
            bfr[j] = *(const bf16x8*)((const char*)sB + boff + j * 1024);
#pragma unroll
        for (int i = 0; i < 4; ++i)
#pragma unroll
            for (int j = 0; j < 4; ++j)
                acc[i][j] = __builtin_amdgcn_mfma_f32_16x16x32_bf16(
                    af[i], bfr[j], acc[i][j], 0, 0, 0);
        __syncthreads();
    }

    const int rl = (lane >> 4) * 4, cl = lane & 15;

#pragma unroll
    for (int i = 0; i < 4; ++i) {
#pragma unroll
        for (int j = 0; j < 4; ++j) {
            int gc = n0 + wn * 64 + j * 16 + cl;
#pragma unroll
            for (int v = 0; v < 4; ++v) {
                int gr = m0 + wm * 64 + i * 16 + rl + v;
                if (gr < M && gc < nvalid) {
                    float val = acc[i][j][v];
                    if (MODE == 2) {
                        ((float*)Cout)[(size_t)gr * ldc + gc] = val;
                    } else {
                        if (MODE == 1 || MODE == 3) val += bias[gc];
                        if (MODE == 1) val = fmaxf(val, 0.f);
                        ((ushort*)Cout)[(size_t)gr * ldc + gc] = f2bf(val);
                    }
                }
            }
        }
    }
}

// ---------------------------------------------------------------------------
// Stage-3b: fused sim filter, epilogue-amortized.
// Identical K-loop + d2 math to gemm_nt (bitwise-equal dots vs stage 3a).
// Each block: one 128-row M-tile x NSUB consecutive 128-col N-tiles.
// Survivors staged in a SEPARATE LDS region (persists across sub-tiles);
// ONE global flush per block (1 atomicAdd per nonempty row) -> the contended
// global-atomic + scattered-store fixed cost is paid 1568x, not 6272x.
// LDS: 16896 (gemm) + 33280 (staging) = 50176 B -> 3 blocks/CU.
// Overflow beyond RCAP3 falls back to direct global append (exactness).
// ---------------------------------------------------------------------------
__global__ __launch_bounds__(256) void filt128(const ushort* __restrict__ A,
                                               const ushort* __restrict__ Bv,
                                               const float* __restrict__ q2v,
                                               const float* __restrict__ c2v,
                                               const float* __restrict__ thrv,
                                               float* __restrict__ candV,
                                               int* __restrict__ candI,
                                               int* __restrict__ cnt,
                                               int M, int K, int nvalid) {
    __shared__ __align__(16) char smem[16896];
    __shared__ float stV[128][RCAP3];
    __shared__ int   stI[128][RCAP3];
    __shared__ int   stC[128];
    ushort* sA = (ushort*)smem;
    ushort* sB = (ushort*)(smem + 8192);
    const int t = threadIdx.x;
    const int lane = t & 63, w = t >> 6;
    const int wm = w & 1, wn = w >> 1;
    const int la = lane & 15, lk = lane >> 4;
    const int aoff = (wm * 64 + la) * 64 + lk * 16;
    const int boff = (wn * 64 + la) * 64 + lk * 16;
    const int r_ = t >> 2, cc_ = (t & 3);
    const int rl = lk * 4, cl = la;

    // block -> (mt, grp): XCD-chunked so the 8 M-tile sharers of each B-group
    // are co-resident on one XCD (grp-major within wu).
    const int wu = (blockIdx.x & 7) * NGRP + (blockIdx.x >> 3);
    const int mt = wu & 7, grp = wu >> 3;
    const int m0 = mt * 128;

    for (int r = t; r < 128; r += 256) stC[r] = 0;
    // (first K-loop __syncthreads makes the init visible before any append)

    // hoist per-row constants (independent of sub-tile)
    float q2r[4][4], thrr[4][4];
#pragma unroll
    for (int i = 0; i < 4; ++i)
#pragma unroll
        for (int v = 0; v < 4; ++v) {
            int gr = m0 + wm * 64 + i * 16 + rl + v;
            q2r[i][v] = q2v[gr];
            thrr[i][v] = thrv[gr];
        }

    for (int s = 0; s < NSUB; ++s) {
        int ntile = grp * NSUB + s;
        if (ntile >= NT3) break;
        int n0 = ntile * 128;

        f32x4 acc[4][4];
#pragma unroll
        for (int i = 0; i < 4; ++i)
#pragma unroll
            for (int j = 0; j < 4; ++j)
                acc[i][j] = (f32x4){0.f, 0.f, 0.f, 0.f};

        for (int k0 = 0; k0 < K; k0 += 32) {
#pragma unroll
            for (int q = 0; q < 2; ++q) {
                int r = r_ + q * 64;
                int ar = m0 + r; ar = (ar < M) ? ar : (M - 1);
                GLDS(A + (size_t)ar * K + k0 + cc_ * 8,
                     (char*)sA + (q * 256 + t) * 16);
                int br = n0 + r; br = (br < nvalid) ? br : (nvalid - 1);
                GLDS(Bv + (size_t)br * K + k0 + cc_ * 8,
                     (char*)sB + (q * 256 + t) * 16);
            }
            __syncthreads();
            bf16x8 af[4], bfr[4];
#pragma unroll
            for (int i = 0; i < 4; ++i)
                af[i] = *(const bf16x8*)((const char*)sA + aoff + i * 1024);
#pragma unroll
            for (int j = 0; j < 4; ++j)
                bfr[j] = *(const bf16x8*)((const char*)sB + boff + j * 1024);
#pragma unroll
            for (int i = 0; i < 4; ++i)
#pragma unroll
                for (int j = 0; j < 4; ++j)
                    acc[i][j] = __builtin_amdgcn_mfma_f32_16x16x32_bf16(
                        af[i], bfr[j], acc[i][j], 0, 0, 0);
            __syncthreads();
        }

        // filter this sub-tile into LDS staging (regs + staging region only --
        // no hazard with the next sub-tile's sA/sB staging)
#pragma unroll
        for (int i = 0; i < 4; ++i) {
#pragma unroll
            for (int j = 0; j < 4; ++j) {
                int gc = n0 + wn * 64 + j * 16 + cl;
                if (gc < nvalid) {
                    float c2c = c2v[gc];
#pragma unroll
                    for (int v = 0; v < 4; ++v) {
                        float d2 = d2_of(acc[i][j][v], q2r[i][v], c2c);
                        if (d2 <= thrr[i][v]) {
                            int rloc = wm * 64 + i * 16 + rl + v;
                            int p = atomicAdd(&stC[rloc], 1);
                            if (p < RCAP3) {
                                stV[rloc][p] = d2;
                                stI[rloc][p] = gc;
                            } else {
                                int gr = m0 + rloc;
                                int gp = atomicAdd(&cnt[gr], 1);
                                if (gp < CAPC) {
                                    candV[(size_t)gr * CAPC + gp] = d2;
                                    candI[(size_t)gr * CAPC + gp] = gc;
                                }
                            }
                        }
                    }
                }
            }
        }
    }

    __syncthreads();
    // single flush: one global atomic per nonempty row per block
    for (int r = t; r < 128; r += 256) {
        int n = stC[r]; if (n > RCAP3) n = RCAP3;
        if (n > 0) {
            int gr = m0 + r;
            int gb = atomicAdd(&cnt[gr], n);
            for (int q = 0; q < n; ++q) {
                int pos = gb + q;
                if (pos < CAPC) {
                    candV[(size_t)gr * CAPC + pos] = stV[r][q];
                    candI[(size_t)gr * CAPC + pos] = stI[r][q];
                }
            }
        }
    }
}

// ---------------------------------------------------------------------------
// per-row radix-select of the 96th-SMALLEST d^2 over the first SAMP columns.
// ---------------------------------------------------------------------------
__global__ __launch_bounds__(256) void thr_select(const float* __restrict__ S,
                                                  int ld,
                                                  const float* __restrict__ q2v,
                                                  const float* __restrict__ c2v,
                                                  float* __restrict__ thrArr) {
    __shared__ unsigned keys[SAMP];
    __shared__ int hist[256];
    __shared__ int sel[2];
    const int b = blockIdx.x, t = threadIdx.x;
    const float q2b = q2v[b];
    for (int i = t; i < SAMP; i += 256)
        keys[i] = ~f2key(d2_of(S[(size_t)b * ld + i], q2b, c2v[i]));
    __syncthreads();
    unsigned prefix = 0, mask = 0;
    int rank = K_;
    for (int shift = 24; shift >= 0; shift -= 8) {
        hist[t & 255] = 0;
        __syncthreads();
        for (int i = t; i < SAMP; i += 256) {
            unsigned k = keys[i];
            if ((k & mask) == prefix) atomicAdd(&hist[(k >> shift) & 255], 1);
        }
        __syncthreads();
        if (t == 0) {
            int r = rank, d = 255;
            for (; d > 0; --d) { int c = hist[d]; if (r - c <= 0) break; r -= c; }
            sel[0] = d; sel[1] = (r < 1) ? 1 : r;
        }
        __syncthreads();
        prefix |= ((unsigned)sel[0]) << shift;
        rank = sel[1];
        mask |= (0xFFu << shift);
        __syncthreads();
    }
    if (t == 0) {
        unsigned key = ~prefix;
        thrArr[b] = __uint_as_float(key & 0x7FFFFFFFu);
    }
}

// ---------------------------------------------------------------------------
// per-row exact 96-smallest-d2 from candidate buffer via radix select
// (inverted keys) + compaction. topV receives d2.
// ---------------------------------------------------------------------------
__global__ __launch_bounds__(256) void final_select(const float* __restrict__ candV,
                                                    const int* __restrict__ candI,
                                                    const int* __restrict__ cnt,
                                                    float* __restrict__ topV,
                                                    int* __restrict__ topI) {
    __shared__ unsigned keys[CAPC];
    __shared__ int hist[256];
    __shared__ int sel[2];
    __shared__ int poscnt, eqcnt;
    const int b = blockIdx.x, t = threadIdx.x;
    int n = cnt[b]; if (n > CAPC) n = CAPC;
    for (int i = t; i < n; i += 256)
        keys[i] = ~f2key(candV[(size_t)b * CAPC + i]);
    __syncthreads();
    unsigned prefix = 0, mask = 0;
    int rank = K_;
    for (int shift = 24; shift >= 0; shift -= 8) {
        hist[t & 255] = 0;
        __syncthreads();
        for (int i = t; i < n; i += 256) {
            unsigned k = keys[i];
            if ((k & mask) == prefix) atomicAdd(&hist[(k >> shift) & 255], 1);
        }
        __syncthreads();
        if (t == 0) {
            int r = rank, d = 255;
            for (; d > 0; --d) { int c = hist[d]; if (r - c <= 0) break; r -= c; }
            sel[0] = d; sel[1] = (r < 1) ? 1 : r;
        }
        __syncthreads();
        prefix |= ((unsigned)sel[0]) << shift;
        rank = sel[1];
        mask |= (0xFFu << shift);
        __syncthreads();
    }
    unsigned kth = prefix;
    if (t == 0) { poscnt = 0; eqcnt = 0; }
    __syncthreads();
    for (int i = t; i < n; i += 256) {
        if (keys[i] > kth) {
            int p = atomicAdd(&poscnt, 1);
            topV[b * K_ + p] = candV[(size_t)b * CAPC + i];
            topI[b * K_ + p] = candI[(size_t)b * CAPC + i];
        }
    }
    __syncthreads();
    int base = poscnt;
    for (int i = t; i < n; i += 256) {
        if (keys[i] == kth) {
            int p = atomicAdd(&eqcnt, 1);
            if (base + p < K_) {
                topV[b * K_ + base + p] = candV[(size_t)b * CAPC + i];
                topI[b * K_ + base + p] = candI[(size_t)b * CAPC + i];
            }
        }
    }
}

__global__ void init_cnt(int* cnt) {
    int i = blockIdx.x * 256 + threadIdx.x;
    if (i < B_) cnt[i] = 0;
}

// ---------------------------------------------------------------------------
__global__ void conv_f2b(const float* __restrict__ in, ushort* __restrict__ out, int n) {
    int i = (blockIdx.x * 256 + threadIdx.x) * 4;
    int stride = gridDim.x * 256 * 4;
    for (; i < n; i += stride) {
        float4 v = *(const float4*)(in + i);
        ushort4 o;
        o.x = f2bf(v.x); o.y = f2bf(v.y); o.z = f2bf(v.z); o.w = f2bf(v.w);
        *(ushort4*)(out + i) = o;
    }
}

__global__ __launch_bounds__(256) void transpose_f2b(const float* __restrict__ in,
                                                     ushort* __restrict__ out,
                                                     int R, int Cn) {
    __shared__ float tile[32][33];
    int bx = blockIdx.x * 32, by = blockIdx.y * 32;
    int tx = threadIdx.x & 31, ty = threadIdx.x >> 5;
    int x = bx + tx;
#pragma unroll
    for (int dy = 0; dy < 32; dy += 8) {
        int y = by + ty + dy;
        if (x < Cn && y < R) tile[ty + dy][tx] = in[(size_t)y * Cn + x];
    }
    __syncthreads();
    int ox = by + tx;
#pragma unroll
    for (int dy = 0; dy < 32; dy += 8) {
        int oy = bx + ty + dy;
        if (ox < R && oy < Cn) out[(size_t)oy * R + ox] = f2bf(tile[tx][ty + dy]);
    }
}

__global__ __launch_bounds__(64) void rowsq_b(const ushort* __restrict__ X,
                                              float* __restrict__ outv) {
    const int r = blockIdx.x, t = threadIdx.x;
    const ushort* p = X + (size_t)r * H_;
    ushort4 a = *(const ushort4*)(p + t * 4);
    ushort4 b = *(const ushort4*)(p + 256 + t * 4);
    float ax = bf2f(a.x), ay = bf2f(a.y), az = bf2f(a.z), aw = bf2f(a.w);
    float bx = bf2f(b.x), by = bf2f(b.y), bz = bf2f(b.z), bw = bf2f(b.w);
    float v = ax * ax + ay * ay + az * az + aw * aw +
              bx * bx + by * by + bz * bz + bw * bw;
    for (int off = 32; off > 0; off >>= 1) v += __shfl_down(v, off);
    if (t == 0) outv[r] = v;
}

// q2x[b] = ||xkb[b,:]||^2 - 2 * dot(xk[b,:], bc)   (folds the bias term of
// sim = xproj.cx + xk.bc into the per-row q2 constant)
__global__ __launch_bounds__(64) void q2x_k(const ushort* __restrict__ Xb,
                                            const float* __restrict__ Xf,
                                            const float* __restrict__ bc,
                                            float* __restrict__ outv) {
    const int r = blockIdx.x, t = threadIdx.x;
    const ushort* p  = Xb + (size_t)r * H_ + t * 8;
    const float*  xf = Xf + (size_t)r * H_ + t * 8;
    float nrm = 0.f, dot = 0.f;
#pragma unroll
    for (int j = 0; j < 8; ++j) {
        float v = bf2f(p[j]);
        nrm = fmaf(v, v, nrm);
        dot = fmaf(xf[j], bc[t * 8 + j], dot);
    }
    for (int off = 32; off > 0; off >>= 1) {
        nrm += __shfl_down(nrm, off);
        dot += __shfl_down(dot, off);
    }
    if (t == 0) outv[r] = nrm - 2.f * dot;
}

__global__ void bcomb_k(const float* __restrict__ b_enc,
                        const float* __restrict__ W_key,
                        const float* __restrict__ b_key,
                        float* __restrict__ b_comb) {
    int h = blockIdx.x * 256 + threadIdx.x;
    if (h >= H_) return;
    float acc = b_key[h];
    for (int m = 0; m < H_; ++m)
        acc = fmaf(b_enc[m], W_key[(size_t)m * H_ + h], acc);
    b_comb[h] = acc;
}

__global__ __launch_bounds__(128) void softmax_k(const float* __restrict__ topVal,
                                                 float* __restrict__ attn) {
    __shared__ float red[128];
    const int b = blockIdx.x, t = threadIdx.x;
    float v = (t < K_) ? -sqrtf(topVal[b * K_ + t]) : -FLT_MAX;
    red[t] = v; __syncthreads();
    for (int s = 64; s > 0; s >>= 1) {
        if (t < s) red[t] = fmaxf(red[t], red[t + s]);
        __syncthreads();
    }
    float m = red[0]; __syncthreads();
    float e = (t < K_) ? expf(v - m) : 0.f;
    red[t] = e; __syncthreads();
    for (int s = 64; s > 0; s >>= 1) {
        if (t < s) red[t] += red[t + s];
        __syncthreads();
    }
    float ssum = red[0];
    if (t < K_) attn[b * K_ + t] = e / ssum;
}

__global__ __launch_bounds__(128) void gather_diff_b(const float* __restrict__ XK,
                                                     const ushort* __restrict__ CK,
                                                     const int* __restrict__ topI,
                                                     ushort* __restrict__ diff,
                                                     int b0) {
    const int r = blockIdx.x;
    const int b = b0 + r / K_;
    const int idx = topI[b * K_ + (r % K_)];
    const int t = threadIdx.x;
    float4 xv = *(const float4*)(XK + (size_t)b * H_ + t * 4);
    ushort4 cv = *(const ushort4*)(CK + (size_t)idx * H_ + t * 4);
    ushort4 o;
    o.x = f2bf(xv.x - bf2f(cv.x));
    o.y = f2bf(xv.y - bf2f(cv.y));
    o.z = f2bf(xv.z - bf2f(cv.z));
    o.w = f2bf(xv.w - bf2f(cv.w));
    *(ushort4*)(diff + (size_t)r * H_ + t * 4) = o;
}

// attn-weighted reduction of h over k (BEFORE the W_t2 GEMM):
// hw[b,:] = sum_k attn[b,k] * h[(b-b0)*K+k, :]   (fp32 accum -> bf16)
__global__ __launch_bounds__(256) void wsum_h(const float* __restrict__ attn,
                                              const ushort* __restrict__ h,
                                              ushort* __restrict__ hw, int b0) {
    const int bl = blockIdx.x;
    const int b = b0 + bl;
    const int t = threadIdx.x;
    float a0 = 0.f, a1 = 0.f;
    const float* ap = attn + b * K_;
    for (int k = 0; k < K_; ++k) {
        float w = ap[k];
        const ushort* hr = h + (size_t)(bl * K_ + k) * H_;
        a0 = fmaf(w, bf2f(hr[t]), a0);
        a1 = fmaf(w, bf2f(hr[t + 256]), a1);
    }
    hw[(size_t)b * H_ + t]       = f2bf(a0);
    hw[(size_t)b * H_ + t + 256] = f2bf(a1);
}

// out = xe + sum_k attn*E[label[topI]] + tsum
__global__ __launch_bounds__(256) void final_out(const float* __restrict__ attn,
                                                 const int* __restrict__ topI,
                                                 const int* __restrict__ labels,
                                                 const float* __restrict__ E,
                                                 const float* __restrict__ tsum,
                                                 const float* __restrict__ xe,
                                                 float* __restrict__ out) {
    const int b = blockIdx.x, t = threadIdx.x;
    float a0 = 0.f, a1 = 0.f;
    for (int k = 0; k < K_; ++k) {
        float w = attn[b * K_ + k];
        int idx = topI[b * K_ + k];
        int lab = labels[idx];
        const float* el = E + (size_t)lab * H_;
        a0 = fmaf(w, el[t], a0);
        a1 = fmaf(w, el[t + 256], a1);
    }
    out[(size_t)b * H_ + t] =
        xe[(size_t)b * H_ + t] + a0 + tsum[(size_t)b * H_ + t];
    out[(size_t)b * H_ + t + 256] =
        xe[(size_t)b * H_ + t + 256] + a1 + tsum[(size_t)b * H_ + t + 256];
}

// ---------------------------------------------------------------------------
extern "C" void kernel_launch(void* const* d_in, const int* in_sizes, int n_in,
                              void* d_out, int out_size, void* d_ws, size_t ws_size,
                              hipStream_t stream) {
    const float* x      = (const float*)d_in[0];
    const float* cx     = (const float*)d_in[1];
    const int*   labels = (const int*)d_in[2];
    const float* W_enc  = (const float*)d_in[3];
    const float* b_enc  = (const float*)d_in[4];
    const float* W_key  = (const float*)d_in[5];
    const float* b_key  = (const float*)d_in[6];
    // d_in[7]=W_val, d_in[8]=b_val dead (gather unused in reference)
    const float* E_label = (const float*)d_in[9];
    const float* W_t1   = (const float*)d_in[10];
    const float* b_t1   = (const float*)d_in[11];
    const float* W_t2   = (const float*)d_in[12];
    float* out = (float*)d_out;

    char* base = (char*)d_ws;
    size_t off = 0;
    auto take = [&](size_t n) -> char* {
        char* p = base + off;
        off = (off + n + 255) & ~(size_t)255;
        return p;
    };
    float*  Wc    = (float*)take((size_t)D_ * H_ * 4);
    float*  bc    = (float*)take((size_t)H_ * 4);
    ushort* WcT   = (ushort*)take((size_t)H_ * D_ * 2);
    ushort* Wcb   = (ushort*)take((size_t)D_ * H_ * 2);   // Wc bf16 [D,H] rows=d
    ushort* Wt1T  = (ushort*)take((size_t)H_ * H_ * 2);
    ushort* Wt2T  = (ushort*)take((size_t)H_ * H_ * 2);
    float*  xe    = (float*)take((size_t)B_ * H_ * 4);
    float*  xk    = (float*)take((size_t)B_ * H_ * 4);
    ushort* xkb   = (ushort*)take((size_t)B_ * H_ * 2);
    ushort* xprojb= (ushort*)take((size_t)B_ * D_ * 2);   // xk @ Wc^T, bf16
    float*  q2x   = (float*)take((size_t)B_ * 4);
    ushort* ckb   = (ushort*)take((size_t)N_ * H_ * 2);
    float*  c2    = (float*)take((size_t)N_ * 4);
    float*  topV  = (float*)take((size_t)B_ * K_ * 4);
    int*    topI  = (int*)take((size_t)B_ * K_ * 4);
    float*  thr   = (float*)take((size_t)B_ * 4);
    float*  attn  = (float*)take((size_t)B_ * K_ * 4);
    int*    cnt   = (int*)take((size_t)B_ * 4);
    float*  candV = (float*)take((size_t)B_ * CAPC * 4);
    int*    candI = (int*)take((size_t)B_ * CAPC * 4);
    ushort* hwAll = (ushort*)take((size_t)B_ * H_ * 2);
    float*  tsum  = (float*)take((size_t)B_ * H_ * 4);
    char*   big   = base + off;      // shared: cxb (alive thru 3b) -> stage4 bufs
    size_t rem = (ws_size > off) ? (ws_size - off) : 0;

    ushort* cxb = (ushort*)big;       // N*D*2 = 51.2 MB (dead after stage 3b)
    // simSmall (B*SAMP*4 = 16.8 MB) overlays candV exactly (dead before 3b).
    float* simSmall = (float*)candV;

    long long bcq = (long long)(rem / ((size_t)K_ * H_ * 2 * 2));
    if (bcq > B_) bcq = B_;
    if (bcq < 1) bcq = 1;
    int Bc = (int)bcq;

    // stage 0: combined candidate weights + transposed bf16 weights
    {
        dim3 g(H_ / 64, D_ / 64);
        gemm_nn<0><<<g, 256, 0, stream>>>(W_enc, W_key, nullptr, Wc, D_, H_, H_);
        bcomb_k<<<(H_ + 255) / 256, 256, 0, stream>>>(b_enc, W_key, b_key, bc);
        dim3 gt1((H_ + 31) / 32, (D_ + 31) / 32);
        transpose_f2b<<<gt1, 256, 0, stream>>>(Wc, WcT, D_, H_);
        conv_f2b<<<128, 256, 0, stream>>>(Wc, Wcb, D_ * H_);
        dim3 gt2((H_ + 31) / 32, (H_ + 31) / 32);
        transpose_f2b<<<gt2, 256, 0, stream>>>(W_t1, Wt1T, H_, H_);
        transpose_f2b<<<gt2, 256, 0, stream>>>(W_t2, Wt2T, H_, H_);
    }
    // stage 1: query encodes (fp32, tiny) + bf16 conversions + xproj
    {
        dim3 gx(H_ / 64, B_ / 64);
        gemm_nn<0><<<gx, 256, 0, stream>>>(x, W_enc, b_enc, xe, B_, H_, D_);
        gemm_nn<0><<<gx, 256, 0, stream>>>(x, Wc, bc, xk, B_, H_, D_);
        conv_f2b<<<1024, 256, 0, stream>>>(xk, xkb, B_ * H_);
        conv_f2b<<<2048, 256, 0, stream>>>(cx, cxb, N_ * D_);
        // xproj[B,D] = xk @ Wc^T  (contract over H), bf16 out
        dim3 gp(D_ / 128, B_ / 128);         // (2, 8)
        gemm_nt<0, 0><<<gp, 256, 0, stream>>>(
            xkb, Wcb, nullptr, xprojb, B_, D_, H_, D_, D_, 0);
        q2x_k<<<B_, 64, 0, stream>>>(xkb, xk, bc, q2x);
    }
    // stage 2: candidate keys via bf16 MFMA (bias, no relu), SWZ=2
    {
        int mt = (N_ + 127) / 128;           // 782
        int mper = (mt + 7) / 8;             // 98
        gemm_nt<3, 2><<<8 * mper * 4, 256, 0, stream>>>(
            cxb, WcT, bc, ckb, N_, H_, D_, H_, H_, mper);
    }
    rowsq_b<<<N_, 64, 0, stream>>>(ckb, c2);

    // stage 3a: sample sim GEMM over D-contraction (first SAMP cols, raw dot)
    // sim = xproj . cx  (+ per-row constant folded into q2x)
    {
        int nper = (SAMP / 128 + 7) / 8;     // 4
        gemm_nt<2, 1><<<64 * nper, 256, 0, stream>>>(
            xprojb, cxb, nullptr, simSmall, B_, N_, D_, SAMP, SAMP, nper);
        thr_select<<<B_, 256, 0, stream>>>(simSmall, SAMP, q2x, c2, thr);
    }
    // stage 3b: fused sim filter, epilogue-amortized (NSUB N-tiles/block)
    init_cnt<<<(B_ + 255) / 256, 256, 0, stream>>>(cnt);
    filt128<<<8 * NGRP, 256, 0, stream>>>(
        xprojb, cxb, q2x, c2, thr, candV, candI, cnt, B_, D_, N_);
    final_select<<<B_, 256, 0, stream>>>(candV, candI, cnt, topV, topI);
    softmax_k<<<B_, 128, 0, stream>>>(topV, attn);

    // stage 4: h = relu(diff@W1+b1); hw = sum_k attn*h (BEFORE W2);
    //          tsum = hw @ W2; out = xe + sum_k attn*E[label] + tsum
    ushort* diffB = (ushort*)big;
    ushort* hB = (ushort*)(big + (size_t)Bc * K_ * H_ * 2);
    for (int b0 = 0; b0 < B_; b0 += Bc) {
        int bcn = min(Bc, B_ - b0);
        int Mrows = bcn * K_;
        gather_diff_b<<<Mrows, 128, 0, stream>>>(xk, ckb, topI, diffB, b0);
        int mt4 = (Mrows + 127) / 128;
        int mper4 = (mt4 + 7) / 8;
        gemm_nt<1, 2><<<8 * mper4 * 4, 256, 0, stream>>>(
            diffB, Wt1T, b_t1, hB, Mrows, H_, H_, H_, H_, mper4);
        wsum_h<<<bcn, 256, 0, stream>>>(attn, hB, hwAll, b0);
    }
    {   // tiny GEMM: tsum[1024,512] = hwAll @ Wt2T^T (fp32 out via MODE 2)
        dim3 g(H_ / 128, B_ / 128);          // (4, 8)
        gemm_nt<2, 0><<<g, 256, 0, stream>>>(
            hwAll, Wt2T, nullptr, tsum, B_, H_, H_, H_, H_, 0);
    }
    final_out<<<B_, 256, 0, stream>>>(attn, topI, labels, E_label, tsum, xe, out);
}

// Round 5
// 893.858 us; speedup vs baseline: 1.6596x; 1.1123x over previous
//
#include <hip/hip_runtime.h>
#include <cfloat>
#include <cmath>

#define B_ 1024
#define D_ 256
#define H_ 512
#define N_ 100000
#define K_ 96
#define C_ 10
#define SAMP 4096      // sample columns for threshold estimation (fp32 sims
                       // overlay candV exactly: B*SAMP*4 == B*CAPC*4)
#define CAPC 4096      // per-row candidate capacity (expected ~2344 survivors)
#define RCAP 15        // per-row per-tile LDS staging slots (mean ~3/tile;
                       // overflow falls back to direct global append)

typedef __attribute__((ext_vector_type(8))) short bf16x8;
typedef __attribute__((ext_vector_type(4))) float f32x4;

__device__ __forceinline__ float bf2f(ushort h) {
    union { unsigned u; float f; } v; v.u = ((unsigned)h) << 16; return v.f;
}
__device__ __forceinline__ ushort f2bf(float f) {
    union { float f; unsigned u; } v; v.f = f;
    unsigned u = v.u;
    unsigned r = (u + 0x7fffu + ((u >> 16) & 1u)) >> 16;
    return (ushort)r;
}
// monotone fp32 -> u32 (ascending)
__device__ __forceinline__ unsigned f2key(float f) {
    unsigned u = __float_as_uint(f);
    return (u & 0x80000000u) ? ~u : (u | 0x80000000u);
}
// d^2 from raw dot product -- single definition shared by thr_select and the
// fused filter so sample-column recompute is bitwise identical.
__device__ __forceinline__ float d2_of(float acc, float q2, float c2) {
    return fmaxf(fmaf(-2.f, acc, q2 + c2), 0.f);
}

#define GLDS(g, l)                                                            \
    __builtin_amdgcn_global_load_lds(                                         \
        (const __attribute__((address_space(1))) void*)(g),                   \
        (__attribute__((address_space(3))) void*)(l), 16, 0, 0)

#define FENCE() asm volatile("" ::: "memory")

// ---------------------------------------------------------------------------
// fp32 tiled GEMM (kept for tiny fp32 GEMMs: Wc, xe, xk)
// ---------------------------------------------------------------------------
template <int RELU>
__global__ __launch_bounds__(256) void gemm_nn(const float* __restrict__ A,
                                               const float* __restrict__ Bm,
                                               const float* __restrict__ bias,
                                               float* __restrict__ Cm,
                                               int M, int N, int Kd) {
    __shared__ float sA[16][68];
    __shared__ float sB[16][64];
    const int t  = threadIdx.x;
    const int tx = t & 15, ty = t >> 4;
    const int m0 = blockIdx.y * 64;
    const int n0 = blockIdx.x * 64;
    const int lr = t >> 2;
    const int lk = (t & 3) << 2;
    const int bk = t >> 4;
    const int bn = (t & 15) << 2;

    float acc[4][4] = {};
    for (int k0 = 0; k0 < Kd; k0 += 16) {
        float4 av = make_float4(0.f, 0.f, 0.f, 0.f);
        if (m0 + lr < M)
            av = *(const float4*)(A + (size_t)(m0 + lr) * Kd + k0 + lk);
        sA[lk + 0][lr] = av.x; sA[lk + 1][lr] = av.y;
        sA[lk + 2][lr] = av.z; sA[lk + 3][lr] = av.w;
        float4 bv = *(const float4*)(Bm + (size_t)(k0 + bk) * N + n0 + bn);
        *(float4*)&sB[bk][bn] = bv;
        __syncthreads();
#pragma unroll
        for (int kk = 0; kk < 16; ++kk) {
            float4 a4 = *(const float4*)&sA[kk][ty << 2];
            float4 b4 = *(const float4*)&sB[kk][tx << 2];
            float ar[4] = {a4.x, a4.y, a4.z, a4.w};
            float br[4] = {b4.x, b4.y, b4.z, b4.w};
#pragma unroll
            for (int i = 0; i < 4; ++i)
#pragma unroll
                for (int j = 0; j < 4; ++j)
                    acc[i][j] = fmaf(ar[i], br[j], acc[i][j]);
        }
        __syncthreads();
    }
#pragma unroll
    for (int i = 0; i < 4; ++i) {
        int row = m0 + (ty << 2) + i;
        if (row < M) {
            int col = n0 + (tx << 2);
            float b0 = 0.f, b1 = 0.f, b2 = 0.f, b3 = 0.f;
            if (bias) { b0 = bias[col]; b1 = bias[col + 1]; b2 = bias[col + 2]; b3 = bias[col + 3]; }
            float4 o;
            o.x = acc[i][0] + b0; o.y = acc[i][1] + b1;
            o.z = acc[i][2] + b2; o.w = acc[i][3] + b3;
            if (RELU) {
                o.x = fmaxf(o.x, 0.f); o.y = fmaxf(o.y, 0.f);
                o.z = fmaxf(o.z, 0.f); o.w = fmaxf(o.w, 0.f);
            }
            *(float4*)(Cm + (size_t)row * N + col) = o;
        }
    }
}

// ---------------------------------------------------------------------------
// bf16 MFMA NT GEMM: C = epilogue(A[M,K] @ B[N,K]^T)
// 128x128 tile, BK=32, 4 waves, each 4x4 tiles of 16x16x32 MFMA.
// T3-minimum 2-phase pipeline: double-buffered 2x16KB LDS; next K-step's
// global_load_lds issued BEFORE computing the current step; counted
// s_waitcnt vmcnt(4) (waits the 4 OLDEST = current buffer; robust even if
// the compiler interleaves extra vmem ops) + raw s_barrier -- the HBM/L2
// latency hides under the previous step's 16 MFMA. Trailing barrier carries
// lgkmcnt(0) so no wave's buffer is overwritten while ds_reads are in
// flight. Accumulation stays ascending 32-k chunks (bitwise-identical dots
// across all users -> threshold semantics exact).
// SWZ=0: 2-D grid. SWZ=1: 1-D grid, 8 M-tiles sharing a B-tile on one XCD
// (needs M==1024). SWZ=2: 1-D grid, 4 N-tiles sharing an A-tile on one XCD
// (needs Nlim==512).
// MODE 0: out bf16     MODE 1: +bias, relu, out bf16
// MODE 2: raw dot product -> fp32 Cout
// MODE 3: +bias (no relu), out bf16
// MODE 5: fused sim filter: d2<=thr[row] survivors staged in reused LDS,
//         per-row batch append to candV/candI (no C written at all)
// ---------------------------------------------------------------------------
template <int MODE, int SWZ>
__global__ __launch_bounds__(256) void gemm_nt(const ushort* __restrict__ A,
                                               const ushort* __restrict__ Bv,
                                               const float* __restrict__ bias,
                                               const float* __restrict__ q2v,
                                               const float* __restrict__ c2v,
                                               const float* __restrict__ thrv,
                                               float* __restrict__ candV,
                                               int* __restrict__ candI,
                                               int* __restrict__ cnt,
                                               void* __restrict__ Cout,
                                               int M, int Nlim, int K,
                                               int ldc, int nvalid, int per) {
    int m0, n0;
    if (SWZ == 0) {
        m0 = blockIdx.y * 128; n0 = blockIdx.x * 128;
    } else if (SWZ == 1) {
        int bid = blockIdx.x;
        int xcd = bid & 7, slot = bid >> 3;
        m0 = (slot & 7) * 128;
        n0 = (xcd * per + (slot >> 3)) * 128;
        if (n0 >= nvalid || m0 >= M) return;
    } else {
        int bid = blockIdx.x;
        int xcd = bid & 7, slot = bid >> 3;
        n0 = (slot & 3) * 128;
        m0 = (xcd * per + (slot >> 2)) * 128;
        if (m0 >= M) return;
    }

    // [2 buf][A 8192 | B 8192]: A at buf*8192, B at 16384 + buf*8192
    __shared__ __align__(16) char smem[32768];
    const int t = threadIdx.x;
    const int lane = t & 63, w = t >> 6;
    const int wm = w & 1, wn = w >> 1;

    f32x4 acc[4][4];
#pragma unroll
    for (int i = 0; i < 4; ++i)
#pragma unroll
        for (int j = 0; j < 4; ++j)
            acc[i][j] = (f32x4){0.f, 0.f, 0.f, 0.f};

    const int la = lane & 15, lk = lane >> 4;
    const int aoff = (wm * 64 + la) * 64 + lk * 16;
    const int boff = (wn * 64 + la) * 64 + lk * 16;
    const int r_ = t >> 2, cc_ = (t & 3);

    auto stage = [&](int k0, int buf) {
#pragma unroll
        for (int q = 0; q < 2; ++q) {
            int r = r_ + q * 64;
            int ar = m0 + r; ar = (ar < M) ? ar : (M - 1);
            GLDS(A + (size_t)ar * K + k0 + cc_ * 8,
                 (char*)smem + buf * 8192 + (q * 256 + t) * 16);
            int br = n0 + r; br = (br < Nlim) ? br : (Nlim - 1);
            GLDS(Bv + (size_t)br * K + k0 + cc_ * 8,
                 (char*)smem + 16384 + buf * 8192 + (q * 256 + t) * 16);
        }
    };

    stage(0, 0);
    int cur = 0;
    for (int k0 = 0; k0 < K; k0 += 32) {
        if (k0 + 32 < K) {
            stage(k0 + 32, cur ^ 1);       // prefetch next step into other buf
            FENCE();
            asm volatile("s_waitcnt vmcnt(4)" ::: "memory");  // cur's 4 oldest
        } else {
            FENCE();
            asm volatile("s_waitcnt vmcnt(0)" ::: "memory");
        }
        __builtin_amdgcn_s_barrier(); FENCE();

        bf16x8 af[4], bfr[4];
        const char* pA = (const char*)smem + cur * 8192 + aoff;
        const char* pB = (const char*)smem + 16384 + cur * 8192 + boff;
#pragma unroll
        for (int i = 0; i < 4; ++i)
            af[i] = *(const bf16x8*)(pA + i * 1024);
#pragma unroll
        for (int j = 0; j < 4; ++j)
            bfr[j] = *(const bf16x8*)(pB + j * 1024);
#pragma unroll
        for (int i = 0; i < 4; ++i)
#pragma unroll
            for (int j = 0; j < 4; ++j)
                acc[i][j] = __builtin_amdgcn_mfma_f32_16x16x32_bf16(
                    af[i], bfr[j], acc[i][j], 0, 0, 0);

        FENCE();
        asm volatile("s_waitcnt lgkmcnt(0)" ::: "memory");  // reads done
        __builtin_amdgcn_s_barrier(); FENCE();              // before overwrite
        cur ^= 1;
    }

    const int rl = (lane >> 4) * 4, cl = lane & 15;

    if (MODE == 5) {
        // smem is dead after the final barrier -- reuse as staging.
        float* stV = (float*)smem;               // [128][RCAP] = 7680 B
        int*   stI = (int*)(smem + 7680);        // [128][RCAP] = 7680 B
        int*   stC = (int*)(smem + 15360);       // [128]       =  512 B
        for (int r = t; r < 128; r += 256) stC[r] = 0;
        __syncthreads();
#pragma unroll
        for (int i = 0; i < 4; ++i) {
#pragma unroll
            for (int v = 0; v < 4; ++v) {
                int rloc = wm * 64 + i * 16 + rl + v;
                int gr = m0 + rloc;
                float q2b = q2v[gr];
                float th = thrv[gr];
#pragma unroll
                for (int j = 0; j < 4; ++j) {
                    int gc = n0 + wn * 64 + j * 16 + cl;
                    if (gc < nvalid) {
                        float d2 = d2_of(acc[i][j][v], q2b, c2v[gc]);
                        if (d2 <= th) {
                            int p = atomicAdd(&stC[rloc], 1);
                            if (p < RCAP) {
                                stV[rloc * RCAP + p] = d2;
                                stI[rloc * RCAP + p] = gc;
                            } else {
                                // rare overflow: direct global append (exact)
                                int gp = atomicAdd(&cnt[gr], 1);
                                if (gp < CAPC) {
                                    candV[(size_t)gr * CAPC + gp] = d2;
                                    candI[(size_t)gr * CAPC + gp] = gc;
                                }
                            }
                        }
                    }
                }
            }
        }
        __syncthreads();
        for (int r = t; r < 128; r += 256) {
            int n = stC[r]; if (n > RCAP) n = RCAP;
            if (n > 0) {
                int gr = m0 + r;
                int gb = atomicAdd(&cnt[gr], n);
                for (int q = 0; q < n; ++q) {
                    int pos = gb + q;
                    if (pos < CAPC) {
                        candV[(size_t)gr * CAPC + pos] = stV[r * RCAP + q];
                        candI[(size_t)gr * CAPC + pos] = stI[r * RCAP + q];
                    }
                }
            }
        }
        return;
    }

#pragma unroll
    for (int i = 0; i < 4; ++i) {
#pragma unroll
        for (int j = 0; j < 4; ++j) {
            int gc = n0 + wn * 64 + j * 16 + cl;
#pragma unroll
            for (int v = 0; v < 4; ++v) {
                int gr = m0 + wm * 64 + i * 16 + rl + v;
                if (gr < M && gc < nvalid) {
                    float val = acc[i][j][v];
                    if (MODE == 2) {
                        ((float*)Cout)[(size_t)gr * ldc + gc] = val;
                    } else {
                        if (MODE == 1 || MODE == 3) val += bias[gc];
                        if (MODE == 1) val = fmaxf(val, 0.f);
                        ((ushort*)Cout)[(size_t)gr * ldc + gc] = f2bf(val);
                    }
                }
            }
        }
    }
}

// ---------------------------------------------------------------------------
// per-row radix-select of the 96th-SMALLEST d^2 over the first SAMP columns.
// ---------------------------------------------------------------------------
__global__ __launch_bounds__(256) void thr_select(const float* __restrict__ S,
                                                  int ld,
                                                  const float* __restrict__ q2v,
                                                  const float* __restrict__ c2v,
                                                  float* __restrict__ thrArr) {
    __shared__ unsigned keys[SAMP];
    __shared__ int hist[256];
    __shared__ int sel[2];
    const int b = blockIdx.x, t = threadIdx.x;
    const float q2b = q2v[b];
    for (int i = t; i < SAMP; i += 256)
        keys[i] = ~f2key(d2_of(S[(size_t)b * ld + i], q2b, c2v[i]));
    __syncthreads();
    unsigned prefix = 0, mask = 0;
    int rank = K_;
    for (int shift = 24; shift >= 0; shift -= 8) {
        hist[t & 255] = 0;
        __syncthreads();
        for (int i = t; i < SAMP; i += 256) {
            unsigned k = keys[i];
            if ((k & mask) == prefix) atomicAdd(&hist[(k >> shift) & 255], 1);
        }
        __syncthreads();
        if (t == 0) {
            int r = rank, d = 255;
            for (; d > 0; --d) { int c = hist[d]; if (r - c <= 0) break; r -= c; }
            sel[0] = d; sel[1] = (r < 1) ? 1 : r;
        }
        __syncthreads();
        prefix |= ((unsigned)sel[0]) << shift;
        rank = sel[1];
        mask |= (0xFFu << shift);
        __syncthreads();
    }
    if (t == 0) {
        unsigned key = ~prefix;
        thrArr[b] = __uint_as_float(key & 0x7FFFFFFFu);
    }
}

// ---------------------------------------------------------------------------
// per-row exact 96-smallest-d2 from candidate buffer via radix select
// (inverted keys) + compaction. topV receives d2.
// ---------------------------------------------------------------------------
__global__ __launch_bounds__(256) void final_select(const float* __restrict__ candV,
                                                    const int* __restrict__ candI,
                                                    const int* __restrict__ cnt,
                                                    float* __restrict__ topV,
                                                    int* __restrict__ topI) {
    __shared__ unsigned keys[CAPC];
    __shared__ int hist[256];
    __shared__ int sel[2];
    __shared__ int poscnt, eqcnt;
    const int b = blockIdx.x, t = threadIdx.x;
    int n = cnt[b]; if (n > CAPC) n = CAPC;
    for (int i = t; i < n; i += 256)
        keys[i] = ~f2key(candV[(size_t)b * CAPC + i]);
    __syncthreads();
    unsigned prefix = 0, mask = 0;
    int rank = K_;
    for (int shift = 24; shift >= 0; shift -= 8) {
        hist[t & 255] = 0;
        __syncthreads();
        for (int i = t; i < n; i += 256) {
            unsigned k = keys[i];
            if ((k & mask) == prefix) atomicAdd(&hist[(k >> shift) & 255], 1);
        }
        __syncthreads();
        if (t == 0) {
            int r = rank, d = 255;
            for (; d > 0; --d) { int c = hist[d]; if (r - c <= 0) break; r -= c; }
            sel[0] = d; sel[1] = (r < 1) ? 1 : r;
        }
        __syncthreads();
        prefix |= ((unsigned)sel[0]) << shift;
        rank = sel[1];
        mask |= (0xFFu << shift);
        __syncthreads();
    }
    unsigned kth = prefix;
    if (t == 0) { poscnt = 0; eqcnt = 0; }
    __syncthreads();
    for (int i = t; i < n; i += 256) {
        if (keys[i] > kth) {
            int p = atomicAdd(&poscnt, 1);
            topV[b * K_ + p] = candV[(size_t)b * CAPC + i];
            topI[b * K_ + p] = candI[(size_t)b * CAPC + i];
        }
    }
    __syncthreads();
    int base = poscnt;
    for (int i = t; i < n; i += 256) {
        if (keys[i] == kth) {
            int p = atomicAdd(&eqcnt, 1);
            if (base + p < K_) {
                topV[b * K_ + base + p] = candV[(size_t)b * CAPC + i];
                topI[b * K_ + base + p] = candI[(size_t)b * CAPC + i];
            }
        }
    }
}

__global__ void init_cnt(int* cnt) {
    int i = blockIdx.x * 256 + threadIdx.x;
    if (i < B_) cnt[i] = 0;
}

// ---------------------------------------------------------------------------
__global__ void conv_f2b(const float* __restrict__ in, ushort* __restrict__ out, int n) {
    int i = (blockIdx.x * 256 + threadIdx.x) * 4;
    int stride = gridDim.x * 256 * 4;
    for (; i < n; i += stride) {
        float4 v = *(const float4*)(in + i);
        ushort4 o;
        o.x = f2bf(v.x); o.y = f2bf(v.y); o.z = f2bf(v.z); o.w = f2bf(v.w);
        *(ushort4*)(out + i) = o;
    }
}

__global__ __launch_bounds__(256) void transpose_f2b(const float* __restrict__ in,
                                                     ushort* __restrict__ out,
                                                     int R, int Cn) {
    __shared__ float tile[32][33];
    int bx = blockIdx.x * 32, by = blockIdx.y * 32;
    int tx = threadIdx.x & 31, ty = threadIdx.x >> 5;
    int x = bx + tx;
#pragma unroll
    for (int dy = 0; dy < 32; dy += 8) {
        int y = by + ty + dy;
        if (x < Cn && y < R) tile[ty + dy][tx] = in[(size_t)y * Cn + x];
    }
    __syncthreads();
    int ox = by + tx;
#pragma unroll
    for (int dy = 0; dy < 32; dy += 8) {
        int oy = bx + ty + dy;
        if (ox < R && oy < Cn) out[(size_t)oy * R + ox] = f2bf(tile[tx][ty + dy]);
    }
}

__global__ __launch_bounds__(64) void rowsq_b(const ushort* __restrict__ X,
                                              float* __restrict__ outv) {
    const int r = blockIdx.x, t = threadIdx.x;
    const ushort* p = X + (size_t)r * H_;
    ushort4 a = *(const ushort4*)(p + t * 4);
    ushort4 b = *(const ushort4*)(p + 256 + t * 4);
    float ax = bf2f(a.x), ay = bf2f(a.y), az = bf2f(a.z), aw = bf2f(a.w);
    float bx = bf2f(b.x), by = bf2f(b.y), bz = bf2f(b.z), bw = bf2f(b.w);
    float v = ax * ax + ay * ay + az * az + aw * aw +
              bx * bx + by * by + bz * bz + bw * bw;
    for (int off = 32; off > 0; off >>= 1) v += __shfl_down(v, off);
    if (t == 0) outv[r] = v;
}

// q2x[b] = ||xkb[b,:]||^2 - 2 * dot(xk[b,:], bc)   (folds the bias term of
// sim = xproj.cx + xk.bc into the per-row q2 constant)
__global__ __launch_bounds__(64) void q2x_k(const ushort* __restrict__ Xb,
                                            const float* __restrict__ Xf,
                                            const float* __restrict__ bc,
                                            float* __restrict__ outv) {
    const int r = blockIdx.x, t = threadIdx.x;
    const ushort* p  = Xb + (size_t)r * H_ + t * 8;
    const float*  xf = Xf + (size_t)r * H_ + t * 8;
    float nrm = 0.f, dot = 0.f;
#pragma unroll
    for (int j = 0; j < 8; ++j) {
        float v = bf2f(p[j]);
        nrm = fmaf(v, v, nrm);
        dot = fmaf(xf[j], bc[t * 8 + j], dot);
    }
    for (int off = 32; off > 0; off >>= 1) {
        nrm += __shfl_down(nrm, off);
        dot += __shfl_down(dot, off);
    }
    if (t == 0) outv[r] = nrm - 2.f * dot;
}

__global__ void bcomb_k(const float* __restrict__ b_enc,
                        const float* __restrict__ W_key,
                        const float* __restrict__ b_key,
                        float* __restrict__ b_comb) {
    int h = blockIdx.x * 256 + threadIdx.x;
    if (h >= H_) return;
    float acc = b_key[h];
    for (int m = 0; m < H_; ++m)
        acc = fmaf(b_enc[m], W_key[(size_t)m * H_ + h], acc);
    b_comb[h] = acc;
}

__global__ __launch_bounds__(128) void softmax_k(const float* __restrict__ topVal,
                                                 float* __restrict__ attn) {
    __shared__ float red[128];
    const int b = blockIdx.x, t = threadIdx.x;
    float v = (t < K_) ? -sqrtf(topVal[b * K_ + t]) : -FLT_MAX;
    red[t] = v; __syncthreads();
    for (int s = 64; s > 0; s >>= 1) {
        if (t < s) red[t] = fmaxf(red[t], red[t + s]);
        __syncthreads();
    }
    float m = red[0]; __syncthreads();
    float e = (t < K_) ? expf(v - m) : 0.f;
    red[t] = e; __syncthreads();
    for (int s = 64; s > 0; s >>= 1) {
        if (t < s) red[t] += red[t + s];
        __syncthreads();
    }
    float ssum = red[0];
    if (t < K_) attn[b * K_ + t] = e / ssum;
}

__global__ __launch_bounds__(128) void gather_diff_b(const float* __restrict__ XK,
                                                     const ushort* __restrict__ CK,
                                                     const int* __restrict__ topI,
                                                     ushort* __restrict__ diff,
                                                     int b0) {
    const int r = blockIdx.x;
    const int b = b0 + r / K_;
    const int idx = topI[b * K_ + (r % K_)];
    const int t = threadIdx.x;
    float4 xv = *(const float4*)(XK + (size_t)b * H_ + t * 4);
    ushort4 cv = *(const ushort4*)(CK + (size_t)idx * H_ + t * 4);
    ushort4 o;
    o.x = f2bf(xv.x - bf2f(cv.x));
    o.y = f2bf(xv.y - bf2f(cv.y));
    o.z = f2bf(xv.z - bf2f(cv.z));
    o.w = f2bf(xv.w - bf2f(cv.w));
    *(ushort4*)(diff + (size_t)r * H_ + t * 4) = o;
}

// attn-weighted reduction of h over k (BEFORE the W_t2 GEMM):
// hw[b,:] = sum_k attn[b,k] * h[(b-b0)*K+k, :]   (fp32 accum -> bf16)
__global__ __launch_bounds__(256) void wsum_h(const float* __restrict__ attn,
                                              const ushort* __restrict__ h,
                                              ushort* __restrict__ hw, int b0) {
    const int bl = blockIdx.x;
    const int b = b0 + bl;
    const int t = threadIdx.x;
    float a0 = 0.f, a1 = 0.f;
    const float* ap = attn + b * K_;
    for (int k = 0; k < K_; ++k) {
        float w = ap[k];
        const ushort* hr = h + (size_t)(bl * K_ + k) * H_;
        a0 = fmaf(w, bf2f(hr[t]), a0);
        a1 = fmaf(w, bf2f(hr[t + 256]), a1);
    }
    hw[(size_t)b * H_ + t]       = f2bf(a0);
    hw[(size_t)b * H_ + t + 256] = f2bf(a1);
}

// out = xe + sum_k attn*E[label[topI]] + tsum
__global__ __launch_bounds__(256) void final_out(const float* __restrict__ attn,
                                                 const int* __restrict__ topI,
                                                 const int* __restrict__ labels,
                                                 const float* __restrict__ E,
                                                 const float* __restrict__ tsum,
                                                 const float* __restrict__ xe,
                                                 float* __restrict__ out) {
    const int b = blockIdx.x, t = threadIdx.x;
    float a0 = 0.f, a1 = 0.f;
    for (int k = 0; k < K_; ++k) {
        float w = attn[b * K_ + k];
        int idx = topI[b * K_ + k];
        int lab = labels[idx];
        const float* el = E + (size_t)lab * H_;
        a0 = fmaf(w, el[t], a0);
        a1 = fmaf(w, el[t + 256], a1);
    }
    out[(size_t)b * H_ + t] =
        xe[(size_t)b * H_ + t] + a0 + tsum[(size_t)b * H_ + t];
    out[(size_t)b * H_ + t + 256] =
        xe[(size_t)b * H_ + t + 256] + a1 + tsum[(size_t)b * H_ + t + 256];
}

// ---------------------------------------------------------------------------
extern "C" void kernel_launch(void* const* d_in, const int* in_sizes, int n_in,
                              void* d_out, int out_size, void* d_ws, size_t ws_size,
                              hipStream_t stream) {
    const float* x      = (const float*)d_in[0];
    const float* cx     = (const float*)d_in[1];
    const int*   labels = (const int*)d_in[2];
    const float* W_enc  = (const float*)d_in[3];
    const float* b_enc  = (const float*)d_in[4];
    const float* W_key  = (const float*)d_in[5];
    const float* b_key  = (const float*)d_in[6];
    // d_in[7]=W_val, d_in[8]=b_val dead (gather unused in reference)
    const float* E_label = (const float*)d_in[9];
    const float* W_t1   = (const float*)d_in[10];
    const float* b_t1   = (const float*)d_in[11];
    const float* W_t2   = (const float*)d_in[12];
    float* out = (float*)d_out;

    char* base = (char*)d_ws;
    size_t off = 0;
    auto take = [&](size_t n) -> char* {
        char* p = base + off;
        off = (off + n + 255) & ~(size_t)255;
        return p;
    };
    float*  Wc    = (float*)take((size_t)D_ * H_ * 4);
    float*  bc    = (float*)take((size_t)H_ * 4);
    ushort* WcT   = (ushort*)take((size_t)H_ * D_ * 2);
    ushort* Wcb   = (ushort*)take((size_t)D_ * H_ * 2);   // Wc bf16 [D,H] rows=d
    ushort* Wt1T  = (ushort*)take((size_t)H_ * H_ * 2);
    ushort* Wt2T  = (ushort*)take((size_t)H_ * H_ * 2);
    float*  xe    = (float*)take((size_t)B_ * H_ * 4);
    float*  xk    = (float*)take((size_t)B_ * H_ * 4);
    ushort* xkb   = (ushort*)take((size_t)B_ * H_ * 2);
    ushort* xprojb= (ushort*)take((size_t)B_ * D_ * 2);   // xk @ Wc^T, bf16
    float*  q2x   = (float*)take((size_t)B_ * 4);
    ushort* ckb   = (ushort*)take((size_t)N_ * H_ * 2);
    float*  c2    = (float*)take((size_t)N_ * 4);
    float*  topV  = (float*)take((size_t)B_ * K_ * 4);
    int*    topI  = (int*)take((size_t)B_ * K_ * 4);
    float*  thr   = (float*)take((size_t)B_ * 4);
    float*  attn  = (float*)take((size_t)B_ * K_ * 4);
    int*    cnt   = (int*)take((size_t)B_ * 4);
    float*  candV = (float*)take((size_t)B_ * CAPC * 4);
    int*    candI = (int*)take((size_t)B_ * CAPC * 4);
    ushort* hwAll = (ushort*)take((size_t)B_ * H_ * 2);
    float*  tsum  = (float*)take((size_t)B_ * H_ * 4);
    char*   big   = base + off;      // shared: cxb (alive thru 3b) -> stage4 bufs
    size_t rem = (ws_size > off) ? (ws_size - off) : 0;

    ushort* cxb = (ushort*)big;       // N*D*2 = 51.2 MB (dead after stage 3b)
    // simSmall (B*SAMP*4 = 16.8 MB) overlays candV exactly (dead before 3b).
    float* simSmall = (float*)candV;

    long long bcq = (long long)(rem / ((size_t)K_ * H_ * 2 * 2));
    if (bcq > B_) bcq = B_;
    if (bcq < 1) bcq = 1;
    int Bc = (int)bcq;

    // stage 0: combined candidate weights + transposed bf16 weights
    {
        dim3 g(H_ / 64, D_ / 64);
        gemm_nn<0><<<g, 256, 0, stream>>>(W_enc, W_key, nullptr, Wc, D_, H_, H_);
        bcomb_k<<<(H_ + 255) / 256, 256, 0, stream>>>(b_enc, W_key, b_key, bc);
        dim3 gt1((H_ + 31) / 32, (D_ + 31) / 32);
        transpose_f2b<<<gt1, 256, 0, stream>>>(Wc, WcT, D_, H_);
        conv_f2b<<<128, 256, 0, stream>>>(Wc, Wcb, D_ * H_);
        dim3 gt2((H_ + 31) / 32, (H_ + 31) / 32);
        transpose_f2b<<<gt2, 256, 0, stream>>>(W_t1, Wt1T, H_, H_);
        transpose_f2b<<<gt2, 256, 0, stream>>>(W_t2, Wt2T, H_, H_);
    }
    // stage 1: query encodes (fp32, tiny) + bf16 conversions + xproj
    {
        dim3 gx(H_ / 64, B_ / 64);
        gemm_nn<0><<<gx, 256, 0, stream>>>(x, W_enc, b_enc, xe, B_, H_, D_);
        gemm_nn<0><<<gx, 256, 0, stream>>>(x, Wc, bc, xk, B_, H_, D_);
        conv_f2b<<<1024, 256, 0, stream>>>(xk, xkb, B_ * H_);
        conv_f2b<<<2048, 256, 0, stream>>>(cx, cxb, N_ * D_);
        // xproj[B,D] = xk @ Wc^T  (contract over H), bf16 out
        dim3 gp(D_ / 128, B_ / 128);         // (2, 8)
        gemm_nt<0, 0><<<gp, 256, 0, stream>>>(
            xkb, Wcb, nullptr, nullptr, nullptr, nullptr, nullptr, nullptr,
            nullptr, xprojb, B_, D_, H_, D_, D_, 0);
        q2x_k<<<B_, 64, 0, stream>>>(xkb, xk, bc, q2x);
    }
    // stage 2: candidate keys via bf16 MFMA (bias, no relu), SWZ=2
    {
        int mt = (N_ + 127) / 128;           // 782
        int mper = (mt + 7) / 8;             // 98
        gemm_nt<3, 2><<<8 * mper * 4, 256, 0, stream>>>(
            cxb, WcT, bc, nullptr, nullptr, nullptr, nullptr, nullptr, nullptr,
            ckb, N_, H_, D_, H_, H_, mper);
    }
    rowsq_b<<<N_, 64, 0, stream>>>(ckb, c2);

    // stage 3a: sample sim GEMM over D-contraction (first SAMP cols, raw dot)
    // sim = xproj . cx  (+ per-row constant folded into q2x)
    {
        int nper = (SAMP / 128 + 7) / 8;     // 4
        gemm_nt<2, 1><<<64 * nper, 256, 0, stream>>>(
            xprojb, cxb, nullptr, nullptr, nullptr, nullptr, nullptr, nullptr,
            nullptr, simSmall, B_, N_, D_, SAMP, SAMP, nper);
        thr_select<<<B_, 256, 0, stream>>>(simSmall, SAMP, q2x, c2, thr);
    }
    // stage 3b: fused sim GEMM (K=256) + in-epilogue threshold filter
    init_cnt<<<(B_ + 255) / 256, 256, 0, stream>>>(cnt);
    {
        int NT = (N_ + 127) / 128;           // 782
        int nper = (NT + 7) / 8;             // 98
        gemm_nt<5, 1><<<64 * nper, 256, 0, stream>>>(
            xprojb, cxb, nullptr, q2x, c2, thr, candV, candI, cnt,
            nullptr, B_, N_, D_, 0, N_, nper);
    }
    final_select<<<B_, 256, 0, stream>>>(candV, candI, cnt, topV, topI);
    softmax_k<<<B_, 128, 0, stream>>>(topV, attn);

    // stage 4: h = relu(diff@W1+b1); hw = sum_k attn*h (BEFORE W2);
    //          tsum = hw @ W2; out = xe + sum_k attn*E[label] + tsum
    ushort* diffB = (ushort*)big;
    ushort* hB = (ushort*)(big + (size_t)Bc * K_ * H_ * 2);
    for (int b0 = 0; b0 < B_; b0 += Bc) {
        int bcn = min(Bc, B_ - b0);
        int Mrows = bcn * K_;
        gather_diff_b<<<Mrows, 128, 0, stream>>>(xk, ckb, topI, diffB, b0);
        int mt4 = (Mrows + 127) / 128;
        int mper4 = (mt4 + 7) / 8;
        gemm_nt<1, 2><<<8 * mper4 * 4, 256, 0, stream>>>(
            diffB, Wt1T, b_t1, nullptr, nullptr, nullptr, nullptr, nullptr,
            nullptr, hB, Mrows, H_, H_, H_, H_, mper4);
        wsum_h<<<bcn, 256, 0, stream>>>(attn, hB, hwAll, b0);
    }
    {   // tiny GEMM: tsum[1024,512] = hwAll @ Wt2T^T (fp32 out via MODE 2)
        dim3 g(H_ / 128, B_ / 128);          // (4, 8)
        gemm_nt<2, 0><<<g, 256, 0, stream>>>(
            hwAll, Wt2T, nullptr, nullptr, nullptr, nullptr, nullptr, nullptr,
            nullptr, tsum, B_, H_, H_, H_, H_, 0);
    }
    final_out<<<B_, 256, 0, stream>>>(attn, topI, labels, E_label, tsum, xe, out);
}

// Round 6
// 854.290 us; speedup vs baseline: 1.7365x; 1.0463x over previous
//
#include <hip/hip_runtime.h>
#include <cfloat>
#include <cmath>

#define B_ 1024
#define D_ 256
#define H_ 512
#define N_ 100000
#define K_ 96
#define C_ 10
#define SAMP 4096      // sample columns for threshold estimation (fp32 sims
                       // overlay candV exactly: B*SAMP*4 == B*CAPC*4)
#define CAPC 4096      // per-row candidate capacity (expected ~2344 survivors)
#define RCAP 15        // per-row per-tile LDS staging slots (mean ~3/tile;
                       // overflow falls back to direct global append)

typedef __attribute__((ext_vector_type(8))) short bf16x8;
typedef __attribute__((ext_vector_type(4))) float f32x4;

__device__ __forceinline__ float bf2f(ushort h) {
    union { unsigned u; float f; } v; v.u = ((unsigned)h) << 16; return v.f;
}
__device__ __forceinline__ ushort f2bf(float f) {
    union { float f; unsigned u; } v; v.f = f;
    unsigned u = v.u;
    unsigned r = (u + 0x7fffu + ((u >> 16) & 1u)) >> 16;
    return (ushort)r;
}
// monotone fp32 -> u32 (ascending)
__device__ __forceinline__ unsigned f2key(float f) {
    unsigned u = __float_as_uint(f);
    return (u & 0x80000000u) ? ~u : (u | 0x80000000u);
}
// d^2 from raw dot product -- single definition shared by thr_select and the
// fused filter so sample-column recompute is bitwise identical.
__device__ __forceinline__ float d2_of(float acc, float q2, float c2) {
    return fmaxf(fmaf(-2.f, acc, q2 + c2), 0.f);
}

#define GLDS(g, l)                                                            \
    __builtin_amdgcn_global_load_lds(                                         \
        (const __attribute__((address_space(1))) void*)(g),                   \
        (__attribute__((address_space(3))) void*)(l), 16, 0, 0)

#define FENCE() asm volatile("" ::: "memory")

// ---------------------------------------------------------------------------
// fp32 tiled GEMM (kept for tiny fp32 GEMMs: Wc, xe, xk)
// ---------------------------------------------------------------------------
template <int RELU>
__global__ __launch_bounds__(256) void gemm_nn(const float* __restrict__ A,
                                               const float* __restrict__ Bm,
                                               const float* __restrict__ bias,
                                               float* __restrict__ Cm,
                                               int M, int N, int Kd) {
    __shared__ float sA[16][68];
    __shared__ float sB[16][64];
    const int t  = threadIdx.x;
    const int tx = t & 15, ty = t >> 4;
    const int m0 = blockIdx.y * 64;
    const int n0 = blockIdx.x * 64;
    const int lr = t >> 2;
    const int lk = (t & 3) << 2;
    const int bk = t >> 4;
    const int bn = (t & 15) << 2;

    float acc[4][4] = {};
    for (int k0 = 0; k0 < Kd; k0 += 16) {
        float4 av = make_float4(0.f, 0.f, 0.f, 0.f);
        if (m0 + lr < M)
            av = *(const float4*)(A + (size_t)(m0 + lr) * Kd + k0 + lk);
        sA[lk + 0][lr] = av.x; sA[lk + 1][lr] = av.y;
        sA[lk + 2][lr] = av.z; sA[lk + 3][lr] = av.w;
        float4 bv = *(const float4*)(Bm + (size_t)(k0 + bk) * N + n0 + bn);
        *(float4*)&sB[bk][bn] = bv;
        __syncthreads();
#pragma unroll
        for (int kk = 0; kk < 16; ++kk) {
            float4 a4 = *(const float4*)&sA[kk][ty << 2];
            float4 b4 = *(const float4*)&sB[kk][tx << 2];
            float ar[4] = {a4.x, a4.y, a4.z, a4.w};
            float br[4] = {b4.x, b4.y, b4.z, b4.w};
#pragma unroll
            for (int i = 0; i < 4; ++i)
#pragma unroll
                for (int j = 0; j < 4; ++j)
                    acc[i][j] = fmaf(ar[i], br[j], acc[i][j]);
        }
        __syncthreads();
    }
#pragma unroll
    for (int i = 0; i < 4; ++i) {
        int row = m0 + (ty << 2) + i;
        if (row < M) {
            int col = n0 + (tx << 2);
            float b0 = 0.f, b1 = 0.f, b2 = 0.f, b3 = 0.f;
            if (bias) { b0 = bias[col]; b1 = bias[col + 1]; b2 = bias[col + 2]; b3 = bias[col + 3]; }
            float4 o;
            o.x = acc[i][0] + b0; o.y = acc[i][1] + b1;
            o.z = acc[i][2] + b2; o.w = acc[i][3] + b3;
            if (RELU) {
                o.x = fmaxf(o.x, 0.f); o.y = fmaxf(o.y, 0.f);
                o.z = fmaxf(o.z, 0.f); o.w = fmaxf(o.w, 0.f);
            }
            *(float4*)(Cm + (size_t)row * N + col) = o;
        }
    }
}

// ---------------------------------------------------------------------------
// bf16 MFMA NT GEMM: C = epilogue(A[M,K] @ B[N,K]^T)
// 128x128 tile, BK=32, 4 waves, each 4x4 tiles of 16x16x32 MFMA.
// T3-minimum 2-phase pipeline (verified R5: -16us on stage 3b): dbuf 2x16KB
// LDS; next K-step's global_load_lds issued BEFORE computing the current
// step; counted s_waitcnt vmcnt(4) + raw s_barrier. Trailing barrier carries
// lgkmcnt(0) so no buffer is overwritten mid-read. Accumulation stays
// ascending 32-k chunks (bitwise-identical dots across all users).
// SWZ=0: 2-D grid. SWZ=1: 1-D grid, 8 M-tiles sharing a B-tile on one XCD
// (needs M==1024). SWZ=2: 1-D grid, 4 N-tiles sharing an A-tile on one XCD
// (needs Nlim==512).
// MODE 0: out bf16     MODE 1: +bias, relu, out bf16
// MODE 2: raw dot product -> fp32 Cout
// MODE 3: +bias (no relu), out bf16
// MODE 4: +bias (no relu), out fp32
// MODE 5: fused sim filter: d2<=thr[row] survivors staged in reused LDS,
//         per-row batch append to candV/candI (no C written at all)
// ---------------------------------------------------------------------------
template <int MODE, int SWZ>
__global__ __launch_bounds__(256) void gemm_nt(const ushort* __restrict__ A,
                                               const ushort* __restrict__ Bv,
                                               const float* __restrict__ bias,
                                               const float* __restrict__ q2v,
                                               const float* __restrict__ c2v,
                                               const float* __restrict__ thrv,
                                               float* __restrict__ candV,
                                               int* __restrict__ candI,
                                               int* __restrict__ cnt,
                                               void* __restrict__ Cout,
                                               int M, int Nlim, int K,
                                               int ldc, int nvalid, int per) {
    int m0, n0;
    if (SWZ == 0) {
        m0 = blockIdx.y * 128; n0 = blockIdx.x * 128;
    } else if (SWZ == 1) {
        int bid = blockIdx.x;
        int xcd = bid & 7, slot = bid >> 3;
        m0 = (slot & 7) * 128;
        n0 = (xcd * per + (slot >> 3)) * 128;
        if (n0 >= nvalid || m0 >= M) return;
    } else {
        int bid = blockIdx.x;
        int xcd = bid & 7, slot = bid >> 3;
        n0 = (slot & 3) * 128;
        m0 = (xcd * per + (slot >> 2)) * 128;
        if (m0 >= M) return;
    }

    // [2 buf][A 8192 | B 8192]: A at buf*8192, B at 16384 + buf*8192
    __shared__ __align__(16) char smem[32768];
    const int t = threadIdx.x;
    const int lane = t & 63, w = t >> 6;
    const int wm = w & 1, wn = w >> 1;

    f32x4 acc[4][4];
#pragma unroll
    for (int i = 0; i < 4; ++i)
#pragma unroll
        for (int j = 0; j < 4; ++j)
            acc[i][j] = (f32x4){0.f, 0.f, 0.f, 0.f};

    const int la = lane & 15, lk = lane >> 4;
    const int aoff = (wm * 64 + la) * 64 + lk * 16;
    const int boff = (wn * 64 + la) * 64 + lk * 16;
    const int r_ = t >> 2, cc_ = (t & 3);

    auto stage = [&](int k0, int buf) {
#pragma unroll
        for (int q = 0; q < 2; ++q) {
            int r = r_ + q * 64;
            int ar = m0 + r; ar = (ar < M) ? ar : (M - 1);
            GLDS(A + (size_t)ar * K + k0 + cc_ * 8,
                 (char*)smem + buf * 8192 + (q * 256 + t) * 16);
            int br = n0 + r; br = (br < Nlim) ? br : (Nlim - 1);
            GLDS(Bv + (size_t)br * K + k0 + cc_ * 8,
                 (char*)smem + 16384 + buf * 8192 + (q * 256 + t) * 16);
        }
    };

    stage(0, 0);
    int cur = 0;
    for (int k0 = 0; k0 < K; k0 += 32) {
        if (k0 + 32 < K) {
            stage(k0 + 32, cur ^ 1);       // prefetch next step into other buf
            FENCE();
            asm volatile("s_waitcnt vmcnt(4)" ::: "memory");  // cur's 4 oldest
        } else {
            FENCE();
            asm volatile("s_waitcnt vmcnt(0)" ::: "memory");
        }
        __builtin_amdgcn_s_barrier(); FENCE();

        bf16x8 af[4], bfr[4];
        const char* pA = (const char*)smem + cur * 8192 + aoff;
        const char* pB = (const char*)smem + 16384 + cur * 8192 + boff;
#pragma unroll
        for (int i = 0; i < 4; ++i)
            af[i] = *(const bf16x8*)(pA + i * 1024);
#pragma unroll
        for (int j = 0; j < 4; ++j)
            bfr[j] = *(const bf16x8*)(pB + j * 1024);
#pragma unroll
        for (int i = 0; i < 4; ++i)
#pragma unroll
            for (int j = 0; j < 4; ++j)
                acc[i][j] = __builtin_amdgcn_mfma_f32_16x16x32_bf16(
                    af[i], bfr[j], acc[i][j], 0, 0, 0);

        FENCE();
        asm volatile("s_waitcnt lgkmcnt(0)" ::: "memory");  // reads done
        __builtin_amdgcn_s_barrier(); FENCE();              // before overwrite
        cur ^= 1;
    }

    const int rl = (lane >> 4) * 4, cl = lane & 15;

    if (MODE == 5) {
        // smem is dead after the final barrier -- reuse as staging.
        float* stV = (float*)smem;               // [128][RCAP] = 7680 B
        int*   stI = (int*)(smem + 7680);        // [128][RCAP] = 7680 B
        int*   stC = (int*)(smem + 15360);       // [128]       =  512 B
        for (int r = t; r < 128; r += 256) stC[r] = 0;
        __syncthreads();
#pragma unroll
        for (int i = 0; i < 4; ++i) {
#pragma unroll
            for (int v = 0; v < 4; ++v) {
                int rloc = wm * 64 + i * 16 + rl + v;
                int gr = m0 + rloc;
                float q2b = q2v[gr];
                float th = thrv[gr];
#pragma unroll
                for (int j = 0; j < 4; ++j) {
                    int gc = n0 + wn * 64 + j * 16 + cl;
                    if (gc < nvalid) {
                        float d2 = d2_of(acc[i][j][v], q2b, c2v[gc]);
                        if (d2 <= th) {
                            int p = atomicAdd(&stC[rloc], 1);
                            if (p < RCAP) {
                                stV[rloc * RCAP + p] = d2;
                                stI[rloc * RCAP + p] = gc;
                            } else {
                                // rare overflow: direct global append (exact)
                                int gp = atomicAdd(&cnt[gr], 1);
                                if (gp < CAPC) {
                                    candV[(size_t)gr * CAPC + gp] = d2;
                                    candI[(size_t)gr * CAPC + gp] = gc;
                                }
                            }
                        }
                    }
                }
            }
        }
        __syncthreads();
        for (int r = t; r < 128; r += 256) {
            int n = stC[r]; if (n > RCAP) n = RCAP;
            if (n > 0) {
                int gr = m0 + r;
                int gb = atomicAdd(&cnt[gr], n);
                for (int q = 0; q < n; ++q) {
                    int pos = gb + q;
                    if (pos < CAPC) {
                        candV[(size_t)gr * CAPC + pos] = stV[r * RCAP + q];
                        candI[(size_t)gr * CAPC + pos] = stI[r * RCAP + q];
                    }
                }
            }
        }
        return;
    }

#pragma unroll
    for (int i = 0; i < 4; ++i) {
#pragma unroll
        for (int j = 0; j < 4; ++j) {
            int gc = n0 + wn * 64 + j * 16 + cl;
#pragma unroll
            for (int v = 0; v < 4; ++v) {
                int gr = m0 + wm * 64 + i * 16 + rl + v;
                if (gr < M && gc < nvalid) {
                    float val = acc[i][j][v];
                    if (MODE == 2) {
                        ((float*)Cout)[(size_t)gr * ldc + gc] = val;
                    } else if (MODE == 4) {
                        ((float*)Cout)[(size_t)gr * ldc + gc] = val + bias[gc];
                    } else {
                        if (MODE == 1 || MODE == 3) val += bias[gc];
                        if (MODE == 1) val = fmaxf(val, 0.f);
                        ((ushort*)Cout)[(size_t)gr * ldc + gc] = f2bf(val);
                    }
                }
            }
        }
    }
}

// ---------------------------------------------------------------------------
// per-row radix-select of the 96th-SMALLEST d^2 over the first SAMP columns.
// ---------------------------------------------------------------------------
__global__ __launch_bounds__(256) void thr_select(const float* __restrict__ S,
                                                  int ld,
                                                  const float* __restrict__ q2v,
                                                  const float* __restrict__ c2v,
                                                  float* __restrict__ thrArr) {
    __shared__ unsigned keys[SAMP];
    __shared__ int hist[256];
    __shared__ int sel[2];
    const int b = blockIdx.x, t = threadIdx.x;
    const float q2b = q2v[b];
    for (int i = t; i < SAMP; i += 256)
        keys[i] = ~f2key(d2_of(S[(size_t)b * ld + i], q2b, c2v[i]));
    __syncthreads();
    unsigned prefix = 0, mask = 0;
    int rank = K_;
    for (int shift = 24; shift >= 0; shift -= 8) {
        hist[t & 255] = 0;
        __syncthreads();
        for (int i = t; i < SAMP; i += 256) {
            unsigned k = keys[i];
            if ((k & mask) == prefix) atomicAdd(&hist[(k >> shift) & 255], 1);
        }
        __syncthreads();
        if (t == 0) {
            int r = rank, d = 255;
            for (; d > 0; --d) { int c = hist[d]; if (r - c <= 0) break; r -= c; }
            sel[0] = d; sel[1] = (r < 1) ? 1 : r;
        }
        __syncthreads();
        prefix |= ((unsigned)sel[0]) << shift;
        rank = sel[1];
        mask |= (0xFFu << shift);
        __syncthreads();
    }
    if (t == 0) {
        unsigned key = ~prefix;
        thrArr[b] = __uint_as_float(key & 0x7FFFFFFFu);
    }
}

// ---------------------------------------------------------------------------
// per-row exact 96-smallest-d2 from candidate buffer via radix select
// (inverted keys) + compaction. topV receives d2.
// ---------------------------------------------------------------------------
__global__ __launch_bounds__(256) void final_select(const float* __restrict__ candV,
                                                    const int* __restrict__ candI,
                                                    const int* __restrict__ cnt,
                                                    float* __restrict__ topV,
                                                    int* __restrict__ topI) {
    __shared__ unsigned keys[CAPC];
    __shared__ int hist[256];
    __shared__ int sel[2];
    __shared__ int poscnt, eqcnt;
    const int b = blockIdx.x, t = threadIdx.x;
    int n = cnt[b]; if (n > CAPC) n = CAPC;
    for (int i = t; i < n; i += 256)
        keys[i] = ~f2key(candV[(size_t)b * CAPC + i]);
    __syncthreads();
    unsigned prefix = 0, mask = 0;
    int rank = K_;
    for (int shift = 24; shift >= 0; shift -= 8) {
        hist[t & 255] = 0;
        __syncthreads();
        for (int i = t; i < n; i += 256) {
            unsigned k = keys[i];
            if ((k & mask) == prefix) atomicAdd(&hist[(k >> shift) & 255], 1);
        }
        __syncthreads();
        if (t == 0) {
            int r = rank, d = 255;
            for (; d > 0; --d) { int c = hist[d]; if (r - c <= 0) break; r -= c; }
            sel[0] = d; sel[1] = (r < 1) ? 1 : r;
        }
        __syncthreads();
        prefix |= ((unsigned)sel[0]) << shift;
        rank = sel[1];
        mask |= (0xFFu << shift);
        __syncthreads();
    }
    unsigned kth = prefix;
    if (t == 0) { poscnt = 0; eqcnt = 0; }
    __syncthreads();
    for (int i = t; i < n; i += 256) {
        if (keys[i] > kth) {
            int p = atomicAdd(&poscnt, 1);
            topV[b * K_ + p] = candV[(size_t)b * CAPC + i];
            topI[b * K_ + p] = candI[(size_t)b * CAPC + i];
        }
    }
    __syncthreads();
    int base = poscnt;
    for (int i = t; i < n; i += 256) {
        if (keys[i] == kth) {
            int p = atomicAdd(&eqcnt, 1);
            if (base + p < K_) {
                topV[b * K_ + base + p] = candV[(size_t)b * CAPC + i];
                topI[b * K_ + base + p] = candI[(size_t)b * CAPC + i];
            }
        }
    }
}

__global__ void init_cnt(int* cnt) {
    int i = blockIdx.x * 256 + threadIdx.x;
    if (i < B_) cnt[i] = 0;
}

// ---------------------------------------------------------------------------
__global__ void conv_f2b(const float* __restrict__ in, ushort* __restrict__ out, int n) {
    int i = (blockIdx.x * 256 + threadIdx.x) * 4;
    int stride = gridDim.x * 256 * 4;
    for (; i < n; i += stride) {
        float4 v = *(const float4*)(in + i);
        ushort4 o;
        o.x = f2bf(v.x); o.y = f2bf(v.y); o.z = f2bf(v.z); o.w = f2bf(v.w);
        *(ushort4*)(out + i) = o;
    }
}

__global__ __launch_bounds__(256) void transpose_f2b(const float* __restrict__ in,
                                                     ushort* __restrict__ out,
                                                     int R, int Cn) {
    __shared__ float tile[32][33];
    int bx = blockIdx.x * 32, by = blockIdx.y * 32;
    int tx = threadIdx.x & 31, ty = threadIdx.x >> 5;
    int x = bx + tx;
#pragma unroll
    for (int dy = 0; dy < 32; dy += 8) {
        int y = by + ty + dy;
        if (x < Cn && y < R) tile[ty + dy][tx] = in[(size_t)y * Cn + x];
    }
    __syncthreads();
    int ox = by + tx;
#pragma unroll
    for (int dy = 0; dy < 32; dy += 8) {
        int oy = bx + ty + dy;
        if (ox < R && oy < Cn) out[(size_t)oy * R + ox] = f2bf(tile[tx][ty + dy]);
    }
}

__global__ __launch_bounds__(64) void rowsq_b(const ushort* __restrict__ X,
                                              float* __restrict__ outv) {
    const int r = blockIdx.x, t = threadIdx.x;
    const ushort* p = X + (size_t)r * H_;
    ushort4 a = *(const ushort4*)(p + t * 4);
    ushort4 b = *(const ushort4*)(p + 256 + t * 4);
    float ax = bf2f(a.x), ay = bf2f(a.y), az = bf2f(a.z), aw = bf2f(a.w);
    float bx = bf2f(b.x), by = bf2f(b.y), bz = bf2f(b.z), bw = bf2f(b.w);
    float v = ax * ax + ay * ay + az * az + aw * aw +
              bx * bx + by * by + bz * bz + bw * bw;
    for (int off = 32; off > 0; off >>= 1) v += __shfl_down(v, off);
    if (t == 0) outv[r] = v;
}

// q2x[b] = ||xkb[b,:]||^2 - 2 * dot(xk[b,:], bc)   (folds the bias term of
// sim = xproj.cx + xk.bc into the per-row q2 constant)
__global__ __launch_bounds__(64) void q2x_k(const ushort* __restrict__ Xb,
                                            const float* __restrict__ Xf,
                                            const float* __restrict__ bc,
                                            float* __restrict__ outv) {
    const int r = blockIdx.x, t = threadIdx.x;
    const ushort* p  = Xb + (size_t)r * H_ + t * 8;
    const float*  xf = Xf + (size_t)r * H_ + t * 8;
    float nrm = 0.f, dot = 0.f;
#pragma unroll
    for (int j = 0; j < 8; ++j) {
        float v = bf2f(p[j]);
        nrm = fmaf(v, v, nrm);
        dot = fmaf(xf[j], bc[t * 8 + j], dot);
    }
    for (int off = 32; off > 0; off >>= 1) {
        nrm += __shfl_down(nrm, off);
        dot += __shfl_down(dot, off);
    }
    if (t == 0) outv[r] = nrm - 2.f * dot;
}

__global__ void bcomb_k(const float* __restrict__ b_enc,
                        const float* __restrict__ W_key,
                        const float* __restrict__ b_key,
                        float* __restrict__ b_comb) {
    int h = blockIdx.x * 256 + threadIdx.x;
    if (h >= H_) return;
    float acc = b_key[h];
    for (int m = 0; m < H_; ++m)
        acc = fmaf(b_enc[m], W_key[(size_t)m * H_ + h], acc);
    b_comb[h] = acc;
}

__global__ __launch_bounds__(128) void softmax_k(const float* __restrict__ topVal,
                                                 float* __restrict__ attn) {
    __shared__ float red[128];
    const int b = blockIdx.x, t = threadIdx.x;
    float v = (t < K_) ? -sqrtf(topVal[b * K_ + t]) : -FLT_MAX;
    red[t] = v; __syncthreads();
    for (int s = 64; s > 0; s >>= 1) {
        if (t < s) red[t] = fmaxf(red[t], red[t + s]);
        __syncthreads();
    }
    float m = red[0]; __syncthreads();
    float e = (t < K_) ? expf(v - m) : 0.f;
    red[t] = e; __syncthreads();
    for (int s = 64; s > 0; s >>= 1) {
        if (t < s) red[t] += red[t + s];
        __syncthreads();
    }
    float ssum = red[0];
    if (t < K_) attn[b * K_ + t] = e / ssum;
}

// ---------------------------------------------------------------------------
// Stage-4 factorized path: h[b,k,:] = relu(P[b,:] - Q[topI[b,k],:]) where
// P = xk@W1 + b1 (fp32), Q = ck@W1 (bf16). Replaces gather_diff + 98304-row
// GEMM + hB round-trip with one dense Q GEMM (same FLOPs) + this fused
// gather/weighted-sum. hw[b,:] = sum_k attn[b,k]*relu(P-Q) -> bf16.
// ---------------------------------------------------------------------------
__global__ __launch_bounds__(256) void wsum_q(const float* __restrict__ attn,
                                              const int* __restrict__ topI,
                                              const float* __restrict__ P,
                                              const ushort* __restrict__ Q,
                                              ushort* __restrict__ hw) {
    __shared__ float aw[K_];
    __shared__ int ai[K_];
    const int b = blockIdx.x, t = threadIdx.x;
    if (t < K_) { aw[t] = attn[b * K_ + t]; ai[t] = topI[b * K_ + t]; }
    __syncthreads();
    const float p0 = P[(size_t)b * H_ + 2 * t];
    const float p1 = P[(size_t)b * H_ + 2 * t + 1];
    float a0 = 0.f, a1 = 0.f;
    for (int k = 0; k < K_; ++k) {
        float w = aw[k];
        ushort2 q = *(const ushort2*)(Q + (size_t)ai[k] * H_ + 2 * t);
        a0 = fmaf(w, fmaxf(p0 - bf2f(q.x), 0.f), a0);
        a1 = fmaf(w, fmaxf(p1 - bf2f(q.y), 0.f), a1);
    }
    ushort2 o; o.x = f2bf(a0); o.y = f2bf(a1);
    *(ushort2*)(hw + (size_t)b * H_ + 2 * t) = o;
}

// legacy fallback kernels (used only if workspace can't hold dense Q)
__global__ __launch_bounds__(128) void gather_diff_b(const float* __restrict__ XK,
                                                     const ushort* __restrict__ CK,
                                                     const int* __restrict__ topI,
                                                     ushort* __restrict__ diff,
                                                     int b0) {
    const int r = blockIdx.x;
    const int b = b0 + r / K_;
    const int idx = topI[b * K_ + (r % K_)];
    const int t = threadIdx.x;
    float4 xv = *(const float4*)(XK + (size_t)b * H_ + t * 4);
    ushort4 cv = *(const ushort4*)(CK + (size_t)idx * H_ + t * 4);
    ushort4 o;
    o.x = f2bf(xv.x - bf2f(cv.x));
    o.y = f2bf(xv.y - bf2f(cv.y));
    o.z = f2bf(xv.z - bf2f(cv.z));
    o.w = f2bf(xv.w - bf2f(cv.w));
    *(ushort4*)(diff + (size_t)r * H_ + t * 4) = o;
}

__global__ __launch_bounds__(256) void wsum_h(const float* __restrict__ attn,
                                              const ushort* __restrict__ h,
                                              ushort* __restrict__ hw, int b0) {
    const int bl = blockIdx.x;
    const int b = b0 + bl;
    const int t = threadIdx.x;
    float a0 = 0.f, a1 = 0.f;
    const float* ap = attn + b * K_;
    for (int k = 0; k < K_; ++k) {
        float w = ap[k];
        const ushort* hr = h + (size_t)(bl * K_ + k) * H_;
        a0 = fmaf(w, bf2f(hr[t]), a0);
        a1 = fmaf(w, bf2f(hr[t + 256]), a1);
    }
    hw[(size_t)b * H_ + t]       = f2bf(a0);
    hw[(size_t)b * H_ + t + 256] = f2bf(a1);
}

// out = xe + sum_k attn*E[label[topI]] + tsum
__global__ __launch_bounds__(256) void final_out(const float* __restrict__ attn,
                                                 const int* __restrict__ topI,
                                                 const int* __restrict__ labels,
                                                 const float* __restrict__ E,
                                                 const float* __restrict__ tsum,
                                                 const float* __restrict__ xe,
                                                 float* __restrict__ out) {
    const int b = blockIdx.x, t = threadIdx.x;
    float a0 = 0.f, a1 = 0.f;
    for (int k = 0; k < K_; ++k) {
        float w = attn[b * K_ + k];
        int idx = topI[b * K_ + k];
        int lab = labels[idx];
        const float* el = E + (size_t)lab * H_;
        a0 = fmaf(w, el[t], a0);
        a1 = fmaf(w, el[t + 256], a1);
    }
    out[(size_t)b * H_ + t] =
        xe[(size_t)b * H_ + t] + a0 + tsum[(size_t)b * H_ + t];
    out[(size_t)b * H_ + t + 256] =
        xe[(size_t)b * H_ + t + 256] + a1 + tsum[(size_t)b * H_ + t + 256];
}

// ---------------------------------------------------------------------------
extern "C" void kernel_launch(void* const* d_in, const int* in_sizes, int n_in,
                              void* d_out, int out_size, void* d_ws, size_t ws_size,
                              hipStream_t stream) {
    const float* x      = (const float*)d_in[0];
    const float* cx     = (const float*)d_in[1];
    const int*   labels = (const int*)d_in[2];
    const float* W_enc  = (const float*)d_in[3];
    const float* b_enc  = (const float*)d_in[4];
    const float* W_key  = (const float*)d_in[5];
    const float* b_key  = (const float*)d_in[6];
    // d_in[7]=W_val, d_in[8]=b_val dead (gather unused in reference)
    const float* E_label = (const float*)d_in[9];
    const float* W_t1   = (const float*)d_in[10];
    const float* b_t1   = (const float*)d_in[11];
    const float* W_t2   = (const float*)d_in[12];
    float* out = (float*)d_out;

    char* base = (char*)d_ws;
    size_t off = 0;
    auto take = [&](size_t n) -> char* {
        char* p = base + off;
        off = (off + n + 255) & ~(size_t)255;
        return p;
    };
    float*  Wc    = (float*)take((size_t)D_ * H_ * 4);
    float*  bc    = (float*)take((size_t)H_ * 4);
    ushort* WcT   = (ushort*)take((size_t)H_ * D_ * 2);
    ushort* Wcb   = (ushort*)take((size_t)D_ * H_ * 2);   // Wc bf16 [D,H] rows=d
    ushort* Wt1T  = (ushort*)take((size_t)H_ * H_ * 2);
    ushort* Wt2T  = (ushort*)take((size_t)H_ * H_ * 2);
    float*  xe    = (float*)take((size_t)B_ * H_ * 4);
    float*  xk    = (float*)take((size_t)B_ * H_ * 4);
    ushort* xkb   = (ushort*)take((size_t)B_ * H_ * 2);
    ushort* xprojb= (ushort*)take((size_t)B_ * D_ * 2);   // xk @ Wc^T, bf16
    float*  q2x   = (float*)take((size_t)B_ * 4);
    ushort* ckb   = (ushort*)take((size_t)N_ * H_ * 2);
    float*  c2    = (float*)take((size_t)N_ * 4);
    float*  topV  = (float*)take((size_t)B_ * K_ * 4);
    int*    topI  = (int*)take((size_t)B_ * K_ * 4);
    float*  thr   = (float*)take((size_t)B_ * 4);
    float*  attn  = (float*)take((size_t)B_ * K_ * 4);
    int*    cnt   = (int*)take((size_t)B_ * 4);
    float*  candV = (float*)take((size_t)B_ * CAPC * 4);
    int*    candI = (int*)take((size_t)B_ * CAPC * 4);
    ushort* hwAll = (ushort*)take((size_t)B_ * H_ * 2);
    float*  tsum  = (float*)take((size_t)B_ * H_ * 4);
    float*  Pbuf  = (float*)take((size_t)B_ * H_ * 4);    // xk@W1+b1, fp32
    char*   big   = base + off;      // shared: cxb (alive thru 3b) -> Q
    size_t rem = (ws_size > off) ? (ws_size - off) : 0;

    ushort* cxb = (ushort*)big;       // N*D*2 = 51.2 MB (dead after stage 3b)
    // simSmall (B*SAMP*4 = 16.8 MB) overlays candV exactly (dead before 3b).
    float* simSmall = (float*)candV;

    // stage 0: combined candidate weights + transposed bf16 weights
    {
        dim3 g(H_ / 64, D_ / 64);
        gemm_nn<0><<<g, 256, 0, stream>>>(W_enc, W_key, nullptr, Wc, D_, H_, H_);
        bcomb_k<<<(H_ + 255) / 256, 256, 0, stream>>>(b_enc, W_key, b_key, bc);
        dim3 gt1((H_ + 31) / 32, (D_ + 31) / 32);
        transpose_f2b<<<gt1, 256, 0, stream>>>(Wc, WcT, D_, H_);
        conv_f2b<<<128, 256, 0, stream>>>(Wc, Wcb, D_ * H_);
        dim3 gt2((H_ + 31) / 32, (H_ + 31) / 32);
        transpose_f2b<<<gt2, 256, 0, stream>>>(W_t1, Wt1T, H_, H_);
        transpose_f2b<<<gt2, 256, 0, stream>>>(W_t2, Wt2T, H_, H_);
    }
    // stage 1: query encodes (fp32, tiny) + bf16 conversions + xproj + P
    {
        dim3 gx(H_ / 64, B_ / 64);
        gemm_nn<0><<<gx, 256, 0, stream>>>(x, W_enc, b_enc, xe, B_, H_, D_);
        gemm_nn<0><<<gx, 256, 0, stream>>>(x, Wc, bc, xk, B_, H_, D_);
        conv_f2b<<<1024, 256, 0, stream>>>(xk, xkb, B_ * H_);
        conv_f2b<<<2048, 256, 0, stream>>>(cx, cxb, N_ * D_);
        // xproj[B,D] = xk @ Wc^T  (contract over H), bf16 out
        dim3 gp(D_ / 128, B_ / 128);         // (2, 8)
        gemm_nt<0, 0><<<gp, 256, 0, stream>>>(
            xkb, Wcb, nullptr, nullptr, nullptr, nullptr, nullptr, nullptr,
            nullptr, xprojb, B_, D_, H_, D_, D_, 0);
        q2x_k<<<B_, 64, 0, stream>>>(xkb, xk, bc, q2x);
        // P[B,H] = xkb @ W_t1 + b_t1, fp32 out (MODE 4)
        dim3 gq(H_ / 128, B_ / 128);         // (4, 8)
        gemm_nt<4, 0><<<gq, 256, 0, stream>>>(
            xkb, Wt1T, b_t1, nullptr, nullptr, nullptr, nullptr, nullptr,
            nullptr, Pbuf, B_, H_, H_, H_, H_, 0);
    }
    // stage 2: candidate keys via bf16 MFMA (bias, no relu), SWZ=2
    {
        int mt = (N_ + 127) / 128;           // 782
        int mper = (mt + 7) / 8;             // 98
        gemm_nt<3, 2><<<8 * mper * 4, 256, 0, stream>>>(
            cxb, WcT, bc, nullptr, nullptr, nullptr, nullptr, nullptr, nullptr,
            ckb, N_, H_, D_, H_, H_, mper);
    }
    rowsq_b<<<N_, 64, 0, stream>>>(ckb, c2);

    // stage 3a: sample sim GEMM over D-contraction (first SAMP cols, raw dot)
    // sim = xproj . cx  (+ per-row constant folded into q2x)
    {
        int nper = (SAMP / 128 + 7) / 8;     // 4
        gemm_nt<2, 1><<<64 * nper, 256, 0, stream>>>(
            xprojb, cxb, nullptr, nullptr, nullptr, nullptr, nullptr, nullptr,
            nullptr, simSmall, B_, N_, D_, SAMP, SAMP, nper);
        thr_select<<<B_, 256, 0, stream>>>(simSmall, SAMP, q2x, c2, thr);
    }
    // stage 3b: fused sim GEMM (K=256) + in-epilogue threshold filter
    init_cnt<<<(B_ + 255) / 256, 256, 0, stream>>>(cnt);
    {
        int NT = (N_ + 127) / 128;           // 782
        int nper = (NT + 7) / 8;             // 98
        gemm_nt<5, 1><<<64 * nper, 256, 0, stream>>>(
            xprojb, cxb, nullptr, q2x, c2, thr, candV, candI, cnt,
            nullptr, B_, N_, D_, 0, N_, nper);
    }
    final_select<<<B_, 256, 0, stream>>>(candV, candI, cnt, topV, topI);
    softmax_k<<<B_, 128, 0, stream>>>(topV, attn);

    // stage 4 (factorized): Q = ckb@W_t1 (bf16, dense over N; cxb now dead);
    // hw[b,:] = sum_k attn*relu(P[b]-Q[topI]); tsum = hw@W2;
    // out = xe + sum_k attn*E[label] + tsum
    if (rem >= (size_t)N_ * H_ * 2) {
        ushort* Qb = (ushort*)big;
        int mt = (N_ + 127) / 128;           // 782
        int mper = (mt + 7) / 8;             // 98
        gemm_nt<0, 2><<<8 * mper * 4, 256, 0, stream>>>(
            ckb, Wt1T, nullptr, nullptr, nullptr, nullptr, nullptr, nullptr,
            nullptr, Qb, N_, H_, H_, H_, H_, mper);
        wsum_q<<<B_, 256, 0, stream>>>(attn, topI, Pbuf, Qb, hwAll);
    } else {
        // fallback: gathered-diff path (chunked)
        long long bcq = (long long)(rem / ((size_t)K_ * H_ * 2 * 2));
        if (bcq > B_) bcq = B_;
        if (bcq < 1) bcq = 1;
        int Bc = (int)bcq;
        ushort* diffB = (ushort*)big;
        ushort* hB = (ushort*)(big + (size_t)Bc * K_ * H_ * 2);
        for (int b0 = 0; b0 < B_; b0 += Bc) {
            int bcn = min(Bc, B_ - b0);
            int Mrows = bcn * K_;
            gather_diff_b<<<Mrows, 128, 0, stream>>>(xk, ckb, topI, diffB, b0);
            int mt4 = (Mrows + 127) / 128;
            int mper4 = (mt4 + 7) / 8;
            gemm_nt<1, 2><<<8 * mper4 * 4, 256, 0, stream>>>(
                diffB, Wt1T, b_t1, nullptr, nullptr, nullptr, nullptr, nullptr,
                nullptr, hB, Mrows, H_, H_, H_, H_, mper4);
            wsum_h<<<bcn, 256, 0, stream>>>(attn, hB, hwAll, b0);
        }
    }
    {   // tiny GEMM: tsum[1024,512] = hwAll @ Wt2T^T (fp32 out via MODE 2)
        dim3 g(H_ / 128, B_ / 128);          // (4, 8)
        gemm_nt<2, 0><<<g, 256, 0, stream>>>(
            hwAll, Wt2T, nullptr, nullptr, nullptr, nullptr, nullptr, nullptr,
            nullptr, tsum, B_, H_, H_, H_, H_, 0);
    }
    final_out<<<B_, 256, 0, stream>>>(attn, topI, labels, E_label, tsum, xe, out);
}

// Round 7
// 835.820 us; speedup vs baseline: 1.7748x; 1.0221x over previous
//
#include <hip/hip_runtime.h>
#include <cfloat>
#include <cmath>

#define B_ 1024
#define D_ 256
#define H_ 512
#define N_ 100000
#define K_ 96
#define C_ 10
#define SAMP 4096      // sample columns for threshold estimation (fp32 sims
                       // overlay candV exactly: B*SAMP*4 == B*CAPC*4)
#define CAPC 4096      // per-row candidate capacity (expected ~2344 survivors)
#define RCAP 15        // per-row per-tile LDS staging slots (mean ~3/tile;
                       // overflow falls back to direct global append)

typedef __attribute__((ext_vector_type(8))) short bf16x8;
typedef __attribute__((ext_vector_type(4))) float f32x4;

__device__ __forceinline__ float bf2f(ushort h) {
    union { unsigned u; float f; } v; v.u = ((unsigned)h) << 16; return v.f;
}
__device__ __forceinline__ ushort f2bf(float f) {
    union { float f; unsigned u; } v; v.f = f;
    unsigned u = v.u;
    unsigned r = (u + 0x7fffu + ((u >> 16) & 1u)) >> 16;
    return (ushort)r;
}
// monotone fp32 -> u32 (ascending)
__device__ __forceinline__ unsigned f2key(float f) {
    unsigned u = __float_as_uint(f);
    return (u & 0x80000000u) ? ~u : (u | 0x80000000u);
}
// d^2 from raw dot product -- single definition shared by thr_select and the
// fused filter so sample-column recompute is bitwise identical.
__device__ __forceinline__ float d2_of(float acc, float q2, float c2) {
    return fmaxf(fmaf(-2.f, acc, q2 + c2), 0.f);
}

#define GLDS(g, l)                                                            \
    __builtin_amdgcn_global_load_lds(                                         \
        (const __attribute__((address_space(1))) void*)(g),                   \
        (__attribute__((address_space(3))) void*)(l), 16, 0, 0)

#define FENCE() asm volatile("" ::: "memory")

// ---------------------------------------------------------------------------
// fp32 tiled GEMM (tiny fp32 GEMMs: Wc, Wq, xe, xk)
// ---------------------------------------------------------------------------
template <int RELU>
__global__ __launch_bounds__(256) void gemm_nn(const float* __restrict__ A,
                                               const float* __restrict__ Bm,
                                               const float* __restrict__ bias,
                                               float* __restrict__ Cm,
                                               int M, int N, int Kd) {
    __shared__ float sA[16][68];
    __shared__ float sB[16][64];
    const int t  = threadIdx.x;
    const int tx = t & 15, ty = t >> 4;
    const int m0 = blockIdx.y * 64;
    const int n0 = blockIdx.x * 64;
    const int lr = t >> 2;
    const int lk = (t & 3) << 2;
    const int bk = t >> 4;
    const int bn = (t & 15) << 2;

    float acc[4][4] = {};
    for (int k0 = 0; k0 < Kd; k0 += 16) {
        float4 av = make_float4(0.f, 0.f, 0.f, 0.f);
        if (m0 + lr < M)
            av = *(const float4*)(A + (size_t)(m0 + lr) * Kd + k0 + lk);
        sA[lk + 0][lr] = av.x; sA[lk + 1][lr] = av.y;
        sA[lk + 2][lr] = av.z; sA[lk + 3][lr] = av.w;
        float4 bv = *(const float4*)(Bm + (size_t)(k0 + bk) * N + n0 + bn);
        *(float4*)&sB[bk][bn] = bv;
        __syncthreads();
#pragma unroll
        for (int kk = 0; kk < 16; ++kk) {
            float4 a4 = *(const float4*)&sA[kk][ty << 2];
            float4 b4 = *(const float4*)&sB[kk][tx << 2];
            float ar[4] = {a4.x, a4.y, a4.z, a4.w};
            float br[4] = {b4.x, b4.y, b4.z, b4.w};
#pragma unroll
            for (int i = 0; i < 4; ++i)
#pragma unroll
                for (int j = 0; j < 4; ++j)
                    acc[i][j] = fmaf(ar[i], br[j], acc[i][j]);
        }
        __syncthreads();
    }
#pragma unroll
    for (int i = 0; i < 4; ++i) {
        int row = m0 + (ty << 2) + i;
        if (row < M) {
            int col = n0 + (tx << 2);
            float b0 = 0.f, b1 = 0.f, b2 = 0.f, b3 = 0.f;
            if (bias) { b0 = bias[col]; b1 = bias[col + 1]; b2 = bias[col + 2]; b3 = bias[col + 3]; }
            float4 o;
            o.x = acc[i][0] + b0; o.y = acc[i][1] + b1;
            o.z = acc[i][2] + b2; o.w = acc[i][3] + b3;
            if (RELU) {
                o.x = fmaxf(o.x, 0.f); o.y = fmaxf(o.y, 0.f);
                o.z = fmaxf(o.z, 0.f); o.w = fmaxf(o.w, 0.f);
            }
            *(float4*)(Cm + (size_t)row * N + col) = o;
        }
    }
}

// ---------------------------------------------------------------------------
// bf16 MFMA NT GEMM: C = epilogue(A[M,K] @ B[N,K]^T)
// 128x128 tile, BK=32, 4 waves, each 4x4 tiles of 16x16x32 MFMA.
// T3-minimum 2-phase pipeline (verified R5: -16us on stage 3b): dbuf 2x16KB
// LDS; next K-step's global_load_lds issued BEFORE computing the current
// step; counted s_waitcnt vmcnt(4) + raw s_barrier. Trailing barrier carries
// lgkmcnt(0) so no buffer is overwritten mid-read. Accumulation stays
// ascending 32-k chunks (bitwise-identical dots across all users).
// SWZ=0: 2-D grid. SWZ=1: 1-D grid, 8 M-tiles sharing a B-tile on one XCD
// (needs M==1024). SWZ=2: 1-D grid, 4 N-tiles sharing an A-tile on one XCD
// (needs Nlim==512).
// MODE 0: out bf16
// MODE 2: raw dot product -> fp32 Cout
// MODE 3: +bias (no relu), out bf16
// MODE 4: +bias (no relu), out fp32
// MODE 5: fused sim filter: d2<=thr[row] survivors staged in reused LDS,
//         per-row batch append to candV/candI (no C written at all)
// MODE 7: c2-only: accumulate ||bf16(acc+bias)||^2 per OUTPUT ROW into
//         c2out (candV arg); NOTHING else written (kills the 102MB ckb
//         write + the rowsq pass)
// ---------------------------------------------------------------------------
template <int MODE, int SWZ>
__global__ __launch_bounds__(256) void gemm_nt(const ushort* __restrict__ A,
                                               const ushort* __restrict__ Bv,
                                               const float* __restrict__ bias,
                                               const float* __restrict__ q2v,
                                               const float* __restrict__ c2v,
                                               const float* __restrict__ thrv,
                                               float* __restrict__ candV,
                                               int* __restrict__ candI,
                                               int* __restrict__ cnt,
                                               void* __restrict__ Cout,
                                               int M, int Nlim, int K,
                                               int ldc, int nvalid, int per) {
    int m0, n0;
    if (SWZ == 0) {
        m0 = blockIdx.y * 128; n0 = blockIdx.x * 128;
    } else if (SWZ == 1) {
        int bid = blockIdx.x;
        int xcd = bid & 7, slot = bid >> 3;
        m0 = (slot & 7) * 128;
        n0 = (xcd * per + (slot >> 3)) * 128;
        if (n0 >= nvalid || m0 >= M) return;
    } else {
        int bid = blockIdx.x;
        int xcd = bid & 7, slot = bid >> 3;
        n0 = (slot & 3) * 128;
        m0 = (xcd * per + (slot >> 2)) * 128;
        if (m0 >= M) return;
    }

    // [2 buf][A 8192 | B 8192]: A at buf*8192, B at 16384 + buf*8192
    __shared__ __align__(16) char smem[32768];
    const int t = threadIdx.x;
    const int lane = t & 63, w = t >> 6;
    const int wm = w & 1, wn = w >> 1;

    f32x4 acc[4][4];
#pragma unroll
    for (int i = 0; i < 4; ++i)
#pragma unroll
        for (int j = 0; j < 4; ++j)
            acc[i][j] = (f32x4){0.f, 0.f, 0.f, 0.f};

    const int la = lane & 15, lk = lane >> 4;
    const int aoff = (wm * 64 + la) * 64 + lk * 16;
    const int boff = (wn * 64 + la) * 64 + lk * 16;
    const int r_ = t >> 2, cc_ = (t & 3);

    auto stage = [&](int k0, int buf) {
#pragma unroll
        for (int q = 0; q < 2; ++q) {
            int r = r_ + q * 64;
            int ar = m0 + r; ar = (ar < M) ? ar : (M - 1);
            GLDS(A + (size_t)ar * K + k0 + cc_ * 8,
                 (char*)smem + buf * 8192 + (q * 256 + t) * 16);
            int br = n0 + r; br = (br < Nlim) ? br : (Nlim - 1);
            GLDS(Bv + (size_t)br * K + k0 + cc_ * 8,
                 (char*)smem + 16384 + buf * 8192 + (q * 256 + t) * 16);
        }
    };

    stage(0, 0);
    int cur = 0;
    for (int k0 = 0; k0 < K; k0 += 32) {
        if (k0 + 32 < K) {
            stage(k0 + 32, cur ^ 1);       // prefetch next step into other buf
            FENCE();
            asm volatile("s_waitcnt vmcnt(4)" ::: "memory");  // cur's 4 oldest
        } else {
            FENCE();
            asm volatile("s_waitcnt vmcnt(0)" ::: "memory");
        }
        __builtin_amdgcn_s_barrier(); FENCE();

        bf16x8 af[4], bfr[4];
        const char* pA = (const char*)smem + cur * 8192 + aoff;
        const char* pB = (const char*)smem + 16384 + cur * 8192 + boff;
#pragma unroll
        for (int i = 0; i < 4; ++i)
            af[i] = *(const bf16x8*)(pA + i * 1024);
#pragma unroll
        for (int j = 0; j < 4; ++j)
            bfr[j] = *(const bf16x8*)(pB + j * 1024);
#pragma unroll
        for (int i = 0; i < 4; ++i)
#pragma unroll
            for (int j = 0; j < 4; ++j)
                acc[i][j] = __builtin_amdgcn_mfma_f32_16x16x32_bf16(
                    af[i], bfr[j], acc[i][j], 0, 0, 0);

        FENCE();
        asm volatile("s_waitcnt lgkmcnt(0)" ::: "memory");  // reads done
        __builtin_amdgcn_s_barrier(); FENCE();              // before overwrite
        cur ^= 1;
    }

    const int rl = (lane >> 4) * 4, cl = lane & 15;

    if (MODE == 7) {
        // per-row ||.||^2 of bf16-rounded (acc+bias): per-thread partial over
        // its 4 cols, shfl-reduce across the 16-lane (la) group, one atomic
        // per row per wave. c2out := candV arg.
#pragma unroll
        for (int i = 0; i < 4; ++i) {
#pragma unroll
            for (int v = 0; v < 4; ++v) {
                int gr = m0 + wm * 64 + i * 16 + rl + v;
                float s = 0.f;
#pragma unroll
                for (int j = 0; j < 4; ++j) {
                    int gc = n0 + wn * 64 + j * 16 + cl;
                    float val = acc[i][j][v] + bias[gc];
                    float vb = bf2f(f2bf(val));
                    s = fmaf(vb, vb, s);
                }
                s += __shfl_xor(s, 1);
                s += __shfl_xor(s, 2);
                s += __shfl_xor(s, 4);
                s += __shfl_xor(s, 8);
                if (cl == 0 && gr < M) atomicAdd(&candV[gr], s);
            }
        }
        return;
    }

    if (MODE == 5) {
        // smem is dead after the final barrier -- reuse as staging.
        float* stV = (float*)smem;               // [128][RCAP] = 7680 B
        int*   stI = (int*)(smem + 7680);        // [128][RCAP] = 7680 B
        int*   stC = (int*)(smem + 15360);       // [128]       =  512 B
        for (int r = t; r < 128; r += 256) stC[r] = 0;
        __syncthreads();
#pragma unroll
        for (int i = 0; i < 4; ++i) {
#pragma unroll
            for (int v = 0; v < 4; ++v) {
                int rloc = wm * 64 + i * 16 + rl + v;
                int gr = m0 + rloc;
                float q2b = q2v[gr];
                float th = thrv[gr];
#pragma unroll
                for (int j = 0; j < 4; ++j) {
                    int gc = n0 + wn * 64 + j * 16 + cl;
                    if (gc < nvalid) {
                        float d2 = d2_of(acc[i][j][v], q2b, c2v[gc]);
                        if (d2 <= th) {
                            int p = atomicAdd(&stC[rloc], 1);
                            if (p < RCAP) {
                                stV[rloc * RCAP + p] = d2;
                                stI[rloc * RCAP + p] = gc;
                            } else {
                                // rare overflow: direct global append (exact)
                                int gp = atomicAdd(&cnt[gr], 1);
                                if (gp < CAPC) {
                                    candV[(size_t)gr * CAPC + gp] = d2;
                                    candI[(size_t)gr * CAPC + gp] = gc;
                                }
                            }
                        }
                    }
                }
            }
        }
        __syncthreads();
        for (int r = t; r < 128; r += 256) {
            int n = stC[r]; if (n > RCAP) n = RCAP;
            if (n > 0) {
                int gr = m0 + r;
                int gb = atomicAdd(&cnt[gr], n);
                for (int q = 0; q < n; ++q) {
                    int pos = gb + q;
                    if (pos < CAPC) {
                        candV[(size_t)gr * CAPC + pos] = stV[r * RCAP + q];
                        candI[(size_t)gr * CAPC + pos] = stI[r * RCAP + q];
                    }
                }
            }
        }
        return;
    }

#pragma unroll
    for (int i = 0; i < 4; ++i) {
#pragma unroll
        for (int j = 0; j < 4; ++j) {
            int gc = n0 + wn * 64 + j * 16 + cl;
#pragma unroll
            for (int v = 0; v < 4; ++v) {
                int gr = m0 + wm * 64 + i * 16 + rl + v;
                if (gr < M && gc < nvalid) {
                    float val = acc[i][j][v];
                    if (MODE == 2) {
                        ((float*)Cout)[(size_t)gr * ldc + gc] = val;
                    } else if (MODE == 4) {
                        ((float*)Cout)[(size_t)gr * ldc + gc] = val + bias[gc];
                    } else {
                        if (MODE == 3) val += bias[gc];
                        ((ushort*)Cout)[(size_t)gr * ldc + gc] = f2bf(val);
                    }
                }
            }
        }
    }
}

// ---------------------------------------------------------------------------
// per-row radix-select of the 96th-SMALLEST d^2 over the first SAMP columns.
// ---------------------------------------------------------------------------
__global__ __launch_bounds__(256) void thr_select(const float* __restrict__ S,
                                                  int ld,
                                                  const float* __restrict__ q2v,
                                                  const float* __restrict__ c2v,
                                                  float* __restrict__ thrArr) {
    __shared__ unsigned keys[SAMP];
    __shared__ int hist[256];
    __shared__ int sel[2];
    const int b = blockIdx.x, t = threadIdx.x;
    const float q2b = q2v[b];
    for (int i = t; i < SAMP; i += 256)
        keys[i] = ~f2key(d2_of(S[(size_t)b * ld + i], q2b, c2v[i]));
    __syncthreads();
    unsigned prefix = 0, mask = 0;
    int rank = K_;
    for (int shift = 24; shift >= 0; shift -= 8) {
        hist[t & 255] = 0;
        __syncthreads();
        for (int i = t; i < SAMP; i += 256) {
            unsigned k = keys[i];
            if ((k & mask) == prefix) atomicAdd(&hist[(k >> shift) & 255], 1);
        }
        __syncthreads();
        if (t == 0) {
            int r = rank, d = 255;
            for (; d > 0; --d) { int c = hist[d]; if (r - c <= 0) break; r -= c; }
            sel[0] = d; sel[1] = (r < 1) ? 1 : r;
        }
        __syncthreads();
        prefix |= ((unsigned)sel[0]) << shift;
        rank = sel[1];
        mask |= (0xFFu << shift);
        __syncthreads();
    }
    if (t == 0) {
        unsigned key = ~prefix;
        thrArr[b] = __uint_as_float(key & 0x7FFFFFFFu);
    }
}

// ---------------------------------------------------------------------------
// per-row exact 96-smallest-d2 from candidate buffer via radix select
// (inverted keys) + compaction. topV receives d2.
// ---------------------------------------------------------------------------
__global__ __launch_bounds__(256) void final_select(const float* __restrict__ candV,
                                                    const int* __restrict__ candI,
                                                    const int* __restrict__ cnt,
                                                    float* __restrict__ topV,
                                                    int* __restrict__ topI) {
    __shared__ unsigned keys[CAPC];
    __shared__ int hist[256];
    __shared__ int sel[2];
    __shared__ int poscnt, eqcnt;
    const int b = blockIdx.x, t = threadIdx.x;
    int n = cnt[b]; if (n > CAPC) n = CAPC;
    for (int i = t; i < n; i += 256)
        keys[i] = ~f2key(candV[(size_t)b * CAPC + i]);
    __syncthreads();
    unsigned prefix = 0, mask = 0;
    int rank = K_;
    for (int shift = 24; shift >= 0; shift -= 8) {
        hist[t & 255] = 0;
        __syncthreads();
        for (int i = t; i < n; i += 256) {
            unsigned k = keys[i];
            if ((k & mask) == prefix) atomicAdd(&hist[(k >> shift) & 255], 1);
        }
        __syncthreads();
        if (t == 0) {
            int r = rank, d = 255;
            for (; d > 0; --d) { int c = hist[d]; if (r - c <= 0) break; r -= c; }
            sel[0] = d; sel[1] = (r < 1) ? 1 : r;
        }
        __syncthreads();
        prefix |= ((unsigned)sel[0]) << shift;
        rank = sel[1];
        mask |= (0xFFu << shift);
        __syncthreads();
    }
    unsigned kth = prefix;
    if (t == 0) { poscnt = 0; eqcnt = 0; }
    __syncthreads();
    for (int i = t; i < n; i += 256) {
        if (keys[i] > kth) {
            int p = atomicAdd(&poscnt, 1);
            topV[b * K_ + p] = candV[(size_t)b * CAPC + i];
            topI[b * K_ + p] = candI[(size_t)b * CAPC + i];
        }
    }
    __syncthreads();
    int base = poscnt;
    for (int i = t; i < n; i += 256) {
        if (keys[i] == kth) {
            int p = atomicAdd(&eqcnt, 1);
            if (base + p < K_) {
                topV[b * K_ + base + p] = candV[(size_t)b * CAPC + i];
                topI[b * K_ + base + p] = candI[(size_t)b * CAPC + i];
            }
        }
    }
}

__global__ void init_cnt(int* cnt) {
    int i = blockIdx.x * 256 + threadIdx.x;
    if (i < B_) cnt[i] = 0;
}

__global__ void init_f32(float* p, int n) {
    int i = blockIdx.x * 256 + threadIdx.x;
    int stride = gridDim.x * 256;
    for (; i < n; i += stride) p[i] = 0.f;
}

// ---------------------------------------------------------------------------
__global__ void conv_f2b(const float* __restrict__ in, ushort* __restrict__ out, int n) {
    int i = (blockIdx.x * 256 + threadIdx.x) * 4;
    int stride = gridDim.x * 256 * 4;
    for (; i < n; i += stride) {
        float4 v = *(const float4*)(in + i);
        ushort4 o;
        o.x = f2bf(v.x); o.y = f2bf(v.y); o.z = f2bf(v.z); o.w = f2bf(v.w);
        *(ushort4*)(out + i) = o;
    }
}

__global__ __launch_bounds__(256) void transpose_f2b(const float* __restrict__ in,
                                                     ushort* __restrict__ out,
                                                     int R, int Cn) {
    __shared__ float tile[32][33];
    int bx = blockIdx.x * 32, by = blockIdx.y * 32;
    int tx = threadIdx.x & 31, ty = threadIdx.x >> 5;
    int x = bx + tx;
#pragma unroll
    for (int dy = 0; dy < 32; dy += 8) {
        int y = by + ty + dy;
        if (x < Cn && y < R) tile[ty + dy][tx] = in[(size_t)y * Cn + x];
    }
    __syncthreads();
    int ox = by + tx;
#pragma unroll
    for (int dy = 0; dy < 32; dy += 8) {
        int oy = bx + ty + dy;
        if (ox < R && oy < Cn) out[(size_t)oy * R + ox] = f2bf(tile[tx][ty + dy]);
    }
}

// q2x[b] = ||xkb[b,:]||^2 - 2 * dot(xk[b,:], bc)   (folds the bias term of
// sim = xproj.cx + xk.bc into the per-row q2 constant)
__global__ __launch_bounds__(64) void q2x_k(const ushort* __restrict__ Xb,
                                            const float* __restrict__ Xf,
                                            const float* __restrict__ bc,
                                            float* __restrict__ outv) {
    const int r = blockIdx.x, t = threadIdx.x;
    const ushort* p  = Xb + (size_t)r * H_ + t * 8;
    const float*  xf = Xf + (size_t)r * H_ + t * 8;
    float nrm = 0.f, dot = 0.f;
#pragma unroll
    for (int j = 0; j < 8; ++j) {
        float v = bf2f(p[j]);
        nrm = fmaf(v, v, nrm);
        dot = fmaf(xf[j], bc[t * 8 + j], dot);
    }
    for (int off = 32; off > 0; off >>= 1) {
        nrm += __shfl_down(nrm, off);
        dot += __shfl_down(dot, off);
    }
    if (t == 0) outv[r] = nrm - 2.f * dot;
}

__global__ void bcomb_k(const float* __restrict__ b_enc,
                        const float* __restrict__ W_key,
                        const float* __restrict__ b_key,
                        float* __restrict__ b_comb) {
    int h = blockIdx.x * 256 + threadIdx.x;
    if (h >= H_) return;
    float acc = b_key[h];
    for (int m = 0; m < H_; ++m)
        acc = fmaf(b_enc[m], W_key[(size_t)m * H_ + h], acc);
    b_comb[h] = acc;
}

// bq[h] = sum_m bc[m] * W1[m,h]   (bias of Q = ck@W1 with ck = cx@Wc + bc)
__global__ void bq_k(const float* __restrict__ bc,
                     const float* __restrict__ W1,
                     float* __restrict__ bq) {
    int h = blockIdx.x * 256 + threadIdx.x;
    if (h >= H_) return;
    float acc = 0.f;
    for (int m = 0; m < H_; ++m)
        acc = fmaf(bc[m], W1[(size_t)m * H_ + h], acc);
    bq[h] = acc;
}

__global__ __launch_bounds__(128) void softmax_k(const float* __restrict__ topVal,
                                                 float* __restrict__ attn) {
    __shared__ float red[128];
    const int b = blockIdx.x, t = threadIdx.x;
    float v = (t < K_) ? -sqrtf(topVal[b * K_ + t]) : -FLT_MAX;
    red[t] = v; __syncthreads();
    for (int s = 64; s > 0; s >>= 1) {
        if (t < s) red[t] = fmaxf(red[t], red[t + s]);
        __syncthreads();
    }
    float m = red[0]; __syncthreads();
    float e = (t < K_) ? expf(v - m) : 0.f;
    red[t] = e; __syncthreads();
    for (int s = 64; s > 0; s >>= 1) {
        if (t < s) red[t] += red[t + s];
        __syncthreads();
    }
    float ssum = red[0];
    if (t < K_) attn[b * K_ + t] = e / ssum;
}

// ---------------------------------------------------------------------------
// Stage-4 factorized: h[b,k,:] = relu(P[b,:] - Q[topI[b,k],:]),
// P = xk@W1 + b1 (fp32), Q = cx@(Wc@W1) + bc@W1 (bf16, D-contraction).
// hw[b,:] = sum_k attn[b,k]*relu(P-Q) -> bf16.
// ---------------------------------------------------------------------------
__global__ __launch_bounds__(256) void wsum_q(const float* __restrict__ attn,
                                              const int* __restrict__ topI,
                                              const float* __restrict__ P,
                                              const ushort* __restrict__ Q,
                                              ushort* __restrict__ hw) {
    __shared__ float aw[K_];
    __shared__ int ai[K_];
    const int b = blockIdx.x, t = threadIdx.x;
    if (t < K_) { aw[t] = attn[b * K_ + t]; ai[t] = topI[b * K_ + t]; }
    __syncthreads();
    const float p0 = P[(size_t)b * H_ + 2 * t];
    const float p1 = P[(size_t)b * H_ + 2 * t + 1];
    float a0 = 0.f, a1 = 0.f;
    for (int k = 0; k < K_; ++k) {
        float w = aw[k];
        ushort2 q = *(const ushort2*)(Q + (size_t)ai[k] * H_ + 2 * t);
        a0 = fmaf(w, fmaxf(p0 - bf2f(q.x), 0.f), a0);
        a1 = fmaf(w, fmaxf(p1 - bf2f(q.y), 0.f), a1);
    }
    ushort2 o; o.x = f2bf(a0); o.y = f2bf(a1);
    *(ushort2*)(hw + (size_t)b * H_ + 2 * t) = o;
}

// out = xe + sum_k attn*E[label[topI]] + tsum
__global__ __launch_bounds__(256) void final_out(const float* __restrict__ attn,
                                                 const int* __restrict__ topI,
                                                 const int* __restrict__ labels,
                                                 const float* __restrict__ E,
                                                 const float* __restrict__ tsum,
                                                 const float* __restrict__ xe,
                                                 float* __restrict__ out) {
    const int b = blockIdx.x, t = threadIdx.x;
    float a0 = 0.f, a1 = 0.f;
    for (int k = 0; k < K_; ++k) {
        float w = attn[b * K_ + k];
        int idx = topI[b * K_ + k];
        int lab = labels[idx];
        const float* el = E + (size_t)lab * H_;
        a0 = fmaf(w, el[t], a0);
        a1 = fmaf(w, el[t + 256], a1);
    }
    out[(size_t)b * H_ + t] =
        xe[(size_t)b * H_ + t] + a0 + tsum[(size_t)b * H_ + t];
    out[(size_t)b * H_ + t + 256] =
        xe[(size_t)b * H_ + t + 256] + a1 + tsum[(size_t)b * H_ + t + 256];
}

// ---------------------------------------------------------------------------
extern "C" void kernel_launch(void* const* d_in, const int* in_sizes, int n_in,
                              void* d_out, int out_size, void* d_ws, size_t ws_size,
                              hipStream_t stream) {
    const float* x      = (const float*)d_in[0];
    const float* cx     = (const float*)d_in[1];
    const int*   labels = (const int*)d_in[2];
    const float* W_enc  = (const float*)d_in[3];
    const float* b_enc  = (const float*)d_in[4];
    const float* W_key  = (const float*)d_in[5];
    const float* b_key  = (const float*)d_in[6];
    // d_in[7]=W_val, d_in[8]=b_val dead (gather unused in reference)
    const float* E_label = (const float*)d_in[9];
    const float* W_t1   = (const float*)d_in[10];
    const float* b_t1   = (const float*)d_in[11];
    const float* W_t2   = (const float*)d_in[12];
    float* out = (float*)d_out;

    char* base = (char*)d_ws;
    size_t off = 0;
    auto take = [&](size_t n) -> char* {
        char* p = base + off;
        off = (off + n + 255) & ~(size_t)255;
        return p;
    };
    float*  Wc    = (float*)take((size_t)D_ * H_ * 4);
    float*  bc    = (float*)take((size_t)H_ * 4);
    ushort* WcT   = (ushort*)take((size_t)H_ * D_ * 2);
    ushort* Wcb   = (ushort*)take((size_t)D_ * H_ * 2);   // Wc bf16 [D,H] rows=d
    float*  Wq    = (float*)take((size_t)D_ * H_ * 4);    // Wc @ W_t1, fp32
    ushort* WqT   = (ushort*)take((size_t)H_ * D_ * 2);   // Wq^T bf16 [H,D]
    float*  bq    = (float*)take((size_t)H_ * 4);         // bc @ W_t1
    ushort* Wt1T  = (ushort*)take((size_t)H_ * H_ * 2);
    ushort* Wt2T  = (ushort*)take((size_t)H_ * H_ * 2);
    float*  xe    = (float*)take((size_t)B_ * H_ * 4);
    float*  xk    = (float*)take((size_t)B_ * H_ * 4);
    ushort* xkb   = (ushort*)take((size_t)B_ * H_ * 2);
    ushort* xprojb= (ushort*)take((size_t)B_ * D_ * 2);   // xk @ Wc^T, bf16
    float*  q2x   = (float*)take((size_t)B_ * 4);
    float*  c2    = (float*)take((size_t)N_ * 4);
    float*  topV  = (float*)take((size_t)B_ * K_ * 4);
    int*    topI  = (int*)take((size_t)B_ * K_ * 4);
    float*  thr   = (float*)take((size_t)B_ * 4);
    float*  attn  = (float*)take((size_t)B_ * K_ * 4);
    int*    cnt   = (int*)take((size_t)B_ * 4);
    float*  candV = (float*)take((size_t)B_ * CAPC * 4);
    int*    candI = (int*)take((size_t)B_ * CAPC * 4);
    ushort* hwAll = (ushort*)take((size_t)B_ * H_ * 2);
    float*  tsum  = (float*)take((size_t)B_ * H_ * 4);
    float*  Pbuf  = (float*)take((size_t)B_ * H_ * 4);    // xk@W1+b1, fp32
    ushort* Qb    = (ushort*)take((size_t)N_ * H_ * 2);   // cx@Wq+bq, bf16
    char*   big   = base + off;

    ushort* cxb = (ushort*)big;       // N*D*2 = 51.2 MB (dead after Q GEMM)
    // simSmall (B*SAMP*4 = 16.8 MB) overlays candV exactly (dead before 3b).
    float* simSmall = (float*)candV;

    // stage 0: combined weights + Q-weights + transposed bf16 weights
    {
        dim3 g(H_ / 64, D_ / 64);
        gemm_nn<0><<<g, 256, 0, stream>>>(W_enc, W_key, nullptr, Wc, D_, H_, H_);
        bcomb_k<<<(H_ + 255) / 256, 256, 0, stream>>>(b_enc, W_key, b_key, bc);
        // Wq = Wc @ W_t1  [D,H], fp32; bq = bc @ W_t1
        gemm_nn<0><<<g, 256, 0, stream>>>(Wc, W_t1, nullptr, Wq, D_, H_, H_);
        bq_k<<<(H_ + 255) / 256, 256, 0, stream>>>(bc, W_t1, bq);
        dim3 gt1((H_ + 31) / 32, (D_ + 31) / 32);
        transpose_f2b<<<gt1, 256, 0, stream>>>(Wc, WcT, D_, H_);
        transpose_f2b<<<gt1, 256, 0, stream>>>(Wq, WqT, D_, H_);
        conv_f2b<<<128, 256, 0, stream>>>(Wc, Wcb, D_ * H_);
        dim3 gt2((H_ + 31) / 32, (H_ + 31) / 32);
        transpose_f2b<<<gt2, 256, 0, stream>>>(W_t1, Wt1T, H_, H_);
        transpose_f2b<<<gt2, 256, 0, stream>>>(W_t2, Wt2T, H_, H_);
    }
    // stage 1: query encodes (fp32, tiny) + bf16 conversions + xproj + P
    {
        dim3 gx(H_ / 64, B_ / 64);
        gemm_nn<0><<<gx, 256, 0, stream>>>(x, W_enc, b_enc, xe, B_, H_, D_);
        gemm_nn<0><<<gx, 256, 0, stream>>>(x, Wc, bc, xk, B_, H_, D_);
        conv_f2b<<<1024, 256, 0, stream>>>(xk, xkb, B_ * H_);
        conv_f2b<<<2048, 256, 0, stream>>>(cx, cxb, N_ * D_);
        // xproj[B,D] = xk @ Wc^T  (contract over H), bf16 out
        dim3 gp(D_ / 128, B_ / 128);         // (2, 8)
        gemm_nt<0, 0><<<gp, 256, 0, stream>>>(
            xkb, Wcb, nullptr, nullptr, nullptr, nullptr, nullptr, nullptr,
            nullptr, xprojb, B_, D_, H_, D_, D_, 0);
        q2x_k<<<B_, 64, 0, stream>>>(xkb, xk, bc, q2x);
        // P[B,H] = xkb @ W_t1 + b_t1, fp32 out (MODE 4)
        dim3 gq(H_ / 128, B_ / 128);         // (4, 8)
        gemm_nt<4, 0><<<gq, 256, 0, stream>>>(
            xkb, Wt1T, b_t1, nullptr, nullptr, nullptr, nullptr, nullptr,
            nullptr, Pbuf, B_, H_, H_, H_, H_, 0);
    }
    // stage 2: candidate-key row norms c2 ONLY (MODE 7) -- ck values are
    // computed in-register and discarded; no 102MB ckb write, no rowsq pass.
    init_f32<<<128, 256, 0, stream>>>(c2, N_);
    {
        int mt = (N_ + 127) / 128;           // 782
        int mper = (mt + 7) / 8;             // 98
        gemm_nt<7, 2><<<8 * mper * 4, 256, 0, stream>>>(
            cxb, WcT, bc, nullptr, nullptr, nullptr, c2, nullptr, nullptr,
            nullptr, N_, H_, D_, H_, H_, mper);
    }

    // stage 3a: sample sim GEMM over D-contraction (first SAMP cols, raw dot)
    // sim = xproj . cx  (+ per-row constant folded into q2x)
    {
        int nper = (SAMP / 128 + 7) / 8;     // 4
        gemm_nt<2, 1><<<64 * nper, 256, 0, stream>>>(
            xprojb, cxb, nullptr, nullptr, nullptr, nullptr, nullptr, nullptr,
            nullptr, simSmall, B_, N_, D_, SAMP, SAMP, nper);
        thr_select<<<B_, 256, 0, stream>>>(simSmall, SAMP, q2x, c2, thr);
    }
    // stage 3b: fused sim GEMM (K=256) + in-epilogue threshold filter
    init_cnt<<<(B_ + 255) / 256, 256, 0, stream>>>(cnt);
    {
        int NT = (N_ + 127) / 128;           // 782
        int nper = (NT + 7) / 8;             // 98
        gemm_nt<5, 1><<<64 * nper, 256, 0, stream>>>(
            xprojb, cxb, nullptr, q2x, c2, thr, candV, candI, cnt,
            nullptr, B_, N_, D_, 0, N_, nper);
    }
    // Q[N,H] = cxb @ WqT^T + bq  (D-contraction: half the FLOPs of ck@W1)
    {
        int mt = (N_ + 127) / 128;           // 782
        int mper = (mt + 7) / 8;             // 98
        gemm_nt<3, 2><<<8 * mper * 4, 256, 0, stream>>>(
            cxb, WqT, bq, nullptr, nullptr, nullptr, nullptr, nullptr,
            nullptr, Qb, N_, H_, D_, H_, H_, mper);
    }
    final_select<<<B_, 256, 0, stream>>>(candV, candI, cnt, topV, topI);
    softmax_k<<<B_, 128, 0, stream>>>(topV, attn);

    // stage 4: hw[b,:] = sum_k attn*relu(P[b]-Q[topI]); tsum = hw@W2;
    // out = xe + sum_k attn*E[label] + tsum
    wsum_q<<<B_, 256, 0, stream>>>(attn, topI, Pbuf, Qb, hwAll);
    {   // tiny GEMM: tsum[1024,512] = hwAll @ Wt2T^T (fp32 out via MODE 2)
        dim3 g(H_ / 128, B_ / 128);          // (4, 8)
        gemm_nt<2, 0><<<g, 256, 0, stream>>>(
            hwAll, Wt2T, nullptr, nullptr, nullptr, nullptr, nullptr, nullptr,
            nullptr, tsum, B_, H_, H_, H_, H_, 0);
    }
    final_out<<<B_, 256, 0, stream>>>(attn, topI, labels, E_label, tsum, xe, out);
}